// Round 2
// 232.591 us; speedup vs baseline: 1.0540x; 1.0540x over previous
//
#include <hip/hip_runtime.h>
#include <hip/hip_bf16.h>

#define L2E 1.4426950408889634f
#define LN2 0.6931471805599453f

__device__ __forceinline__ float fexp2(float x) { return __builtin_amdgcn_exp2f(x); }
__device__ __forceinline__ float flog2(float x) { return __builtin_amdgcn_logf(x); }
__device__ __forceinline__ int uniform(int x) { return __builtin_amdgcn_readfirstlane(x); }
__device__ __forceinline__ float sigmoidf_(float v) { return 1.f / (1.f + fexp2(-v * L2E)); }
__device__ __forceinline__ float softplusf_(float t) {
    return (t > 20.f) ? t : LN2 * flog2(1.f + fexp2(t * L2E));
}

// ---------------- workspace layout (floats), total 18,022,400 = 72.1 MB ----------------
constexpr size_t O_M   = 0;          // [32][1024] LN mean
constexpr size_t O_RS  = 32768;      // [32][1024] LN rstd
constexpr size_t O_G   = 65536;      // [32][128][1024] xi, later y_ssm
constexpr size_t O_Z   = 4259840;    // [32][128][1024] z
constexpr size_t O_XC  = 8454144;    // [32][128][1024] conv+silu out
constexpr size_t O_BM  = 12648448;   // [32][16][1024]
constexpr size_t O_CM  = 13172736;   // [32][16][1024]
constexpr size_t O_DTP = 13697024;   // [32][1024][4] dt-proj pre-softplus
constexpr size_t O_HP  = 13828096;   // [32][32][2][2048]: per-chunk P (→h_init) and E

// ================= K1: LN (in-block) + in-proj GEMM W[256,64] @ XN[64,1024] =================
// grid 2048 = 32 seq * 4 jb * 16 pb; block 256 (16 jt x 16 pt), tile 64j x 64p, K=64.
__global__ __launch_bounds__(256) void k1_ln_inproj(
    const float* __restrict__ x0, const float* __restrict__ x1,
    const float* __restrict__ x2, const float* __restrict__ x3,
    const float* __restrict__ win,
    const float* __restrict__ g1, const float* __restrict__ be1,
    const float* __restrict__ g2, const float* __restrict__ be2,
    const float* __restrict__ g3, const float* __restrict__ be3,
    const float* __restrict__ g4, const float* __restrict__ be4,
    float* __restrict__ ws)
{
    __shared__ float sX[64 * 68];
    __shared__ float sW[64 * 68];
    __shared__ float sM[64], sR[64];
    int bid = blockIdx.x;
    int seq = bid >> 6, jb = (bid >> 4) & 3, pb = bid & 15;
    int branch = seq >> 3, b = seq & 7;
    int tid = threadIdx.x;
    int lane = tid & 63;
    int wq = uniform(tid >> 6);
    const float* xin = (branch==0)?x0:(branch==1)?x1:(branch==2)?x2:x3;
    const float* gam = (branch==0)?g1:(branch==1)?g2:(branch==2)?g3:g4;
    const float* bet = (branch==0)?be1:(branch==1)?be2:(branch==2)?be3:be4;
    const float* xb = xin + (size_t)b * 65536;

    // stage raw X tile [c][p] and W^T tile [c][j]
#pragma unroll
    for (int r = 0; r < 16; ++r) {
        int row = r * 4 + wq;                         // uniform per wave
        sX[row * 68 + lane] = xb[(size_t)row * 1024 + pb * 64 + lane];
        sW[lane * 68 + row] = win[(size_t)(jb * 64 + row) * 64 + lane];
    }
    __syncthreads();
    // per-p LN stats (wave 0)
    if (tid < 64) {
        float sum = 0.f, sq = 0.f;
#pragma unroll
        for (int c = 0; c < 64; ++c) {
            float v = sX[c * 68 + tid];
            sum += v; sq += v * v;
        }
        float mean = sum * (1.f/64.f);
        float var  = sq * (1.f/64.f) - mean * mean;
        float rs   = rsqrtf(var + 1e-5f);
        sM[tid] = mean; sR[tid] = rs;
        if (jb == 0) {
            ws[O_M  + (size_t)seq * 1024 + pb * 64 + tid] = mean;
            ws[O_RS + (size_t)seq * 1024 + pb * 64 + tid] = rs;
        }
    }
    __syncthreads();
    // normalize in LDS
#pragma unroll
    for (int r = 0; r < 16; ++r) {
        int c = r * 4 + wq;
        float v = sX[c * 68 + lane];
        sX[c * 68 + lane] = (v - sM[lane]) * sR[lane] * gam[c] + bet[c];
    }
    __syncthreads();
    // micro-tile 4j x 4p
    int jt = tid >> 4, pt = tid & 15;
    float acc[4][4];
#pragma unroll
    for (int i = 0; i < 4; ++i)
#pragma unroll
        for (int j = 0; j < 4; ++j) acc[i][j] = 0.f;
    for (int c = 0; c < 64; ++c) {
        float4 wv = *(const float4*)&sW[c * 68 + jt * 4];
        float4 xv = *(const float4*)&sX[c * 68 + pt * 4];
        float w[4] = {wv.x, wv.y, wv.z, wv.w};
        float x[4] = {xv.x, xv.y, xv.z, xv.w};
#pragma unroll
        for (int i = 0; i < 4; ++i)
#pragma unroll
            for (int j = 0; j < 4; ++j) acc[i][j] += w[i] * x[j];
    }
    int p0 = pb * 64 + pt * 4;
    float* xi = ws + O_G + (size_t)seq * 131072;
    float* zz = ws + O_Z + (size_t)seq * 131072;
#pragma unroll
    for (int ji = 0; ji < 4; ++ji) {
        int j = jb * 64 + jt * 4 + ji;
        float4 v = make_float4(acc[ji][0], acc[ji][1], acc[ji][2], acc[ji][3]);
        if (j < 128) *(float4*)&xi[(size_t)j * 1024 + p0] = v;
        else         *(float4*)&zz[(size_t)(j - 128) * 1024 + p0] = v;
    }
}

// ================= K2: conv4 + SiLU + x-proj(128->36) — LDS-staged, atomic-free =================
// grid 512 = 32 seq * 16 ptile; block 256 = 4 waves x 64 p-lanes.
// Phase 1: bulk-stage xi tile [128][p0-3 .. p0+63] into LDS (coalesced).
// Phase 2: conv+silu from LDS, write xc to global AND back into the LDS row in place.
// Phase 3: x-proj: wave wq owns output rows j = wq*9 .. wq*9+8 over all 128 d.
//          xc from LDS (conflict-free b32), weights via uniform (scalar-path) loads.
__global__ __launch_bounds__(256) void k2_conv_proj(
    const float* __restrict__ wconv, const float* __restrict__ bconv,
    const float* __restrict__ wxp, float* __restrict__ ws)
{
    __shared__ float sX[128 * 68];    // [d][c], c=0..66 <-> p = p0-3+c (stride 68)
    int bid = blockIdx.x;
    int seq = bid >> 4, ptile = bid & 15;
    int tid = threadIdx.x;
    int lane = tid & 63;
    int wq = uniform(tid >> 6);
    int p0 = ptile * 64;
    int p  = p0 + lane;

    const float* xirow = ws + O_G  + (size_t)seq * 131072;
    float*       xcrow = ws + O_XC + (size_t)seq * 131072;

    // ---- phase 1: stage xi tile ----
#pragma unroll 4
    for (int r = 0; r < 32; ++r) {
        int d = r * 4 + wq;                            // uniform per wave
        const float* row = xirow + (size_t)d * 1024;
        int gp = p0 - 3 + lane;
        sX[d * 68 + lane] = (gp >= 0) ? row[gp] : 0.f;
        if (lane < 3) sX[d * 68 + 64 + lane] = row[p0 + 61 + lane];
    }
    __syncthreads();

    // ---- phase 2: conv4 + silu (wave wq owns d rows wq*32 .. wq*32+31) ----
#pragma unroll 2
    for (int dd = 0; dd < 32; ++dd) {
        int d = wq * 32 + dd;                          // uniform
        float4 wc = *(const float4*)&wconv[d * 4];     // uniform scalar loads
        float v = bconv[d];
        float* rowl = &sX[d * 68];
        v += rowl[lane + 0] * wc.x;
        v += rowl[lane + 1] * wc.y;
        v += rowl[lane + 2] * wc.z;
        v += rowl[lane + 3] * wc.w;
        v = v * sigmoidf_(v);                          // silu
        xcrow[(size_t)d * 1024 + p] = v;               // coalesced global store
        rowl[lane + 3] = v;                            // in-place: reads above precede write
    }
    __syncthreads();

    // ---- phase 3: x-proj, K = 128 ----
    int j0 = uniform(wq * 9);
    const float* __restrict__ w0 = wxp + (size_t)j0 * 128;   // uniform pointer -> scalar loads
    float acc[9];
#pragma unroll
    for (int jj = 0; jj < 9; ++jj) acc[jj] = 0.f;
#pragma unroll 4
    for (int d = 0; d < 128; ++d) {
        float xcv = sX[d * 68 + 3 + lane];             // 2 lanes/bank: conflict-free
#pragma unroll
        for (int jj = 0; jj < 9; ++jj)
            acc[jj] += w0[jj * 128 + d] * xcv;         // v_fmac with SGPR weight
    }

    // ---- write out: j<4 -> dtp, 4..19 -> B, 20..35 -> C (branch is wave-uniform) ----
    float* Bm = ws + O_BM + (size_t)seq * 16384;
    float* Cm = ws + O_CM + (size_t)seq * 16384;
#pragma unroll
    for (int jj = 0; jj < 9; ++jj) {
        int j = j0 + jj;
        float t = acc[jj];
        if (j < 4)       ws[O_DTP + ((size_t)seq * 1024 + p) * 4 + j] = t;
        else if (j < 20) Bm[(size_t)(j - 4)  * 1024 + p] = t;
        else             Cm[(size_t)(j - 20) * 1024 + p] = t;
    }
}

// ================= K3: chunk-parallel scan, 32 chunks of 32 steps =================
// thread -> d-pair 2*(tid>>2), s-quad 4*(tid&3): 8 states.
__device__ __forceinline__ void k3_preload(const float* wdt, const float* bdt,
                                           const float* alog, int d0, int s0,
                                           float4& wdt0, float4& wdt1, float& bdt0, float& bdt1,
                                           float* a2)
{
    wdt0 = *(const float4*)(wdt + d0 * 4);
    wdt1 = *(const float4*)(wdt + (d0 + 1) * 4);
    bdt0 = bdt[d0]; bdt1 = bdt[d0 + 1];
    float4 a0 = *(const float4*)(alog + d0 * 16 + s0);
    float4 a1 = *(const float4*)(alog + (d0 + 1) * 16 + s0);
    a2[0] = -fexp2(a0.x * L2E) * L2E; a2[1] = -fexp2(a0.y * L2E) * L2E;
    a2[2] = -fexp2(a0.z * L2E) * L2E; a2[3] = -fexp2(a0.w * L2E) * L2E;
    a2[4] = -fexp2(a1.x * L2E) * L2E; a2[5] = -fexp2(a1.y * L2E) * L2E;
    a2[6] = -fexp2(a1.z * L2E) * L2E; a2[7] = -fexp2(a1.w * L2E) * L2E;
}

// phase A: local scan (h0=0); emit per-chunk P = exp2(a2*sum_dt) and end-state E
__global__ __launch_bounds__(256) void k3a_scan(const float* __restrict__ wdt,
                                                const float* __restrict__ bdt,
                                                const float* __restrict__ alog,
                                                float* __restrict__ ws)
{
    __shared__ float sXC[128 * 33];
    __shared__ __align__(16) float sB[32 * 16];
    __shared__ __align__(16) float sDtp[32 * 4];
    int bid = blockIdx.x;
    int seq = bid >> 5, ch = bid & 31;
    int lb = ch * 32;
    int tid = threadIdx.x;
    int d0 = (tid >> 2) * 2, s0 = (tid & 3) * 4;

    float4 wdt0, wdt1; float bdt0, bdt1; float a2[8];
    k3_preload(wdt, bdt, alog, d0, s0, wdt0, wdt1, bdt0, bdt1, a2);

    const float* xcg = ws + O_XC + (size_t)seq * 131072;
    const float* Bmg = ws + O_BM + (size_t)seq * 16384;
    for (int i = tid; i < 4096; i += 256) {
        int d = i >> 5, li = i & 31;
        sXC[d * 33 + li] = xcg[(size_t)d * 1024 + lb + li];
    }
    for (int i = tid; i < 512; i += 256) {
        int s = i >> 5, li = i & 31;
        sB[li * 16 + s] = Bmg[(size_t)s * 1024 + lb + li];
    }
    if (tid < 128) sDtp[tid] = ws[O_DTP + ((size_t)seq * 1024 + lb + (tid >> 2)) * 4 + (tid & 3)];
    __syncthreads();

    float h[8];
#pragma unroll
    for (int i = 0; i < 8; ++i) h[i] = 0.f;
    float sdt0 = 0.f, sdt1 = 0.f;
    for (int li = 0; li < 32; ++li) {
        float4 q = *(const float4*)&sDtp[li * 4];
        float dt0 = softplusf_(bdt0 + q.x*wdt0.x + q.y*wdt0.y + q.z*wdt0.z + q.w*wdt0.w);
        float dt1 = softplusf_(bdt1 + q.x*wdt1.x + q.y*wdt1.y + q.z*wdt1.z + q.w*wdt1.w);
        float xc0 = sXC[d0 * 33 + li], xc1 = sXC[(d0 + 1) * 33 + li];
        float dx0 = dt0 * xc0, dx1 = dt1 * xc1;
        float4 Bv = *(const float4*)&sB[li * 16 + s0];
        float bv[4] = {Bv.x, Bv.y, Bv.z, Bv.w};
        sdt0 += dt0; sdt1 += dt1;
#pragma unroll
        for (int ss = 0; ss < 4; ++ss) {
            float e0 = fexp2(dt0 * a2[ss]);
            h[ss] = e0 * h[ss] + dx0 * bv[ss];
            float e1 = fexp2(dt1 * a2[4 + ss]);
            h[4 + ss] = e1 * h[4 + ss] + dx1 * bv[ss];
        }
    }
    float* hp = ws + O_HP + (size_t)(seq * 32 + ch) * 4096;
#pragma unroll
    for (int ss = 0; ss < 4; ++ss) {
        hp[d0 * 16 + s0 + ss]            = fexp2(a2[ss] * sdt0);
        hp[(d0 + 1) * 16 + s0 + ss]      = fexp2(a2[4 + ss] * sdt1);
        hp[2048 + d0 * 16 + s0 + ss]     = h[ss];
        hp[2048 + (d0 + 1) * 16 + s0 + ss] = h[4 + ss];
    }
}

// phase B: sequential prefix compose per seq; h_init overwrites the P slot.
__global__ __launch_bounds__(256) void k3b_compose(float* __restrict__ ws)
{
    int seq = blockIdx.x;
    int tid = threadIdx.x;
    int d0 = (tid >> 2) * 2, s0 = (tid & 3) * 4;
    int i0 = d0 * 16 + s0, i1 = (d0 + 1) * 16 + s0;
    float h[8];
#pragma unroll
    for (int i = 0; i < 8; ++i) h[i] = 0.f;
    float* hpb = ws + O_HP + (size_t)seq * 32 * 4096;
    for (int c = 0; c < 32; ++c) {
        float* hp = hpb + (size_t)c * 4096;
        float4 P0 = *(const float4*)&hp[i0];
        float4 P1 = *(const float4*)&hp[i1];
        float4 E0 = *(const float4*)&hp[2048 + i0];
        float4 E1 = *(const float4*)&hp[2048 + i1];
        *(float4*)&hp[i0] = make_float4(h[0], h[1], h[2], h[3]);
        *(float4*)&hp[i1] = make_float4(h[4], h[5], h[6], h[7]);
        h[0] = P0.x * h[0] + E0.x; h[1] = P0.y * h[1] + E0.y;
        h[2] = P0.z * h[2] + E0.z; h[3] = P0.w * h[3] + E0.w;
        h[4] = P1.x * h[4] + E1.x; h[5] = P1.y * h[5] + E1.y;
        h[6] = P1.z * h[6] + E1.z; h[7] = P1.w * h[7] + E1.w;
    }
}

// phase C: rescan from h_init, emit y into O_G
__global__ __launch_bounds__(256) void k3c_scan_y(const float* __restrict__ wdt,
                                                  const float* __restrict__ bdt,
                                                  const float* __restrict__ alog,
                                                  float* __restrict__ ws)
{
    __shared__ float sXC[128 * 33];
    __shared__ float sY[128 * 33];
    __shared__ __align__(16) float sB[32 * 16];
    __shared__ __align__(16) float sC[32 * 16];
    __shared__ __align__(16) float sDtp[32 * 4];
    int bid = blockIdx.x;
    int seq = bid >> 5, ch = bid & 31;
    int lb = ch * 32;
    int tid = threadIdx.x;
    int sq = tid & 3;
    int d0 = (tid >> 2) * 2, s0 = sq * 4;

    float4 wdt0, wdt1; float bdt0, bdt1; float a2[8];
    k3_preload(wdt, bdt, alog, d0, s0, wdt0, wdt1, bdt0, bdt1, a2);

    const float* xcg = ws + O_XC + (size_t)seq * 131072;
    const float* Bmg = ws + O_BM + (size_t)seq * 16384;
    const float* Cmg = ws + O_CM + (size_t)seq * 16384;
    float*       gg  = ws + O_G  + (size_t)seq * 131072;
    for (int i = tid; i < 4096; i += 256) {
        int d = i >> 5, li = i & 31;
        sXC[d * 33 + li] = xcg[(size_t)d * 1024 + lb + li];
    }
    for (int i = tid; i < 512; i += 256) {
        int s = i >> 5, li = i & 31;
        sB[li * 16 + s] = Bmg[(size_t)s * 1024 + lb + li];
        sC[li * 16 + s] = Cmg[(size_t)s * 1024 + lb + li];
    }
    if (tid < 128) sDtp[tid] = ws[O_DTP + ((size_t)seq * 1024 + lb + (tid >> 2)) * 4 + (tid & 3)];

    const float* hp = ws + O_HP + (size_t)(seq * 32 + ch) * 4096;
    float4 H0 = *(const float4*)&hp[d0 * 16 + s0];
    float4 H1 = *(const float4*)&hp[(d0 + 1) * 16 + s0];
    float h[8] = {H0.x, H0.y, H0.z, H0.w, H1.x, H1.y, H1.z, H1.w};
    __syncthreads();

    for (int li = 0; li < 32; ++li) {
        float4 q = *(const float4*)&sDtp[li * 4];
        float dt0 = softplusf_(bdt0 + q.x*wdt0.x + q.y*wdt0.y + q.z*wdt0.z + q.w*wdt0.w);
        float dt1 = softplusf_(bdt1 + q.x*wdt1.x + q.y*wdt1.y + q.z*wdt1.z + q.w*wdt1.w);
        float xc0 = sXC[d0 * 33 + li], xc1 = sXC[(d0 + 1) * 33 + li];
        float dx0 = dt0 * xc0, dx1 = dt1 * xc1;
        float4 Bv = *(const float4*)&sB[li * 16 + s0];
        float4 Cv = *(const float4*)&sC[li * 16 + s0];
        float bv[4] = {Bv.x, Bv.y, Bv.z, Bv.w};
        float cv[4] = {Cv.x, Cv.y, Cv.z, Cv.w};
        float acc0 = 0.f, acc1 = 0.f;
#pragma unroll
        for (int ss = 0; ss < 4; ++ss) {
            float e0 = fexp2(dt0 * a2[ss]);
            h[ss] = e0 * h[ss] + dx0 * bv[ss];
            acc0 += h[ss] * cv[ss];
            float e1 = fexp2(dt1 * a2[4 + ss]);
            h[4 + ss] = e1 * h[4 + ss] + dx1 * bv[ss];
            acc1 += h[4 + ss] * cv[ss];
        }
        acc0 += __shfl_xor(acc0, 1); acc0 += __shfl_xor(acc0, 2);
        acc1 += __shfl_xor(acc1, 1); acc1 += __shfl_xor(acc1, 2);
        if (sq == 0) {
            sY[d0 * 33 + li]       = acc0;
            sY[(d0 + 1) * 33 + li] = acc1;
        }
    }
    __syncthreads();
    for (int i = tid; i < 4096; i += 256) {
        int d = i >> 5, li = i & 31;
        gg[(size_t)d * 1024 + lb + li] = sY[d * 33 + li];
    }
}

// ================= K4: gate + out-proj Wout[64,128] @ G[128,1024] + skip =================
// grid 512 = 32 seq * 16 pb; block 256 (16 ct x 16 pt), tile 64c x 64p, K=128 in 2 halves.
__global__ __launch_bounds__(256) void k4_out(
    const float* __restrict__ x0, const float* __restrict__ x1,
    const float* __restrict__ x2, const float* __restrict__ x3,
    const float* __restrict__ g1, const float* __restrict__ be1,
    const float* __restrict__ g2, const float* __restrict__ be2,
    const float* __restrict__ g3, const float* __restrict__ be3,
    const float* __restrict__ g4, const float* __restrict__ be4,
    const float* __restrict__ dpar, const float* __restrict__ woutp,
    const float* __restrict__ skipp, const float* __restrict__ ws,
    float* __restrict__ out)
{
    __shared__ float sG[64 * 68];
    __shared__ float sW[64 * 68];
    int bid = blockIdx.x;
    int seq = bid >> 4, pb = bid & 15;
    int branch = seq >> 3, b = seq & 7;
    int tid = threadIdx.x;
    int lane = tid & 63;
    int wq = uniform(tid >> 6);
    int ct = tid >> 4, pt = tid & 15;

    const float* ys = ws + O_G  + (size_t)seq * 131072;
    const float* zz = ws + O_Z  + (size_t)seq * 131072;
    const float* xc = ws + O_XC + (size_t)seq * 131072;

    float acc[4][4];
#pragma unroll
    for (int i = 0; i < 4; ++i)
#pragma unroll
        for (int j = 0; j < 4; ++j) acc[i][j] = 0.f;

    for (int hf = 0; hf < 2; ++hf) {
#pragma unroll
        for (int r = 0; r < 16; ++r) {
            int row = r * 4 + wq;                    // uniform
            sW[lane * 68 + row] = woutp[(size_t)row * 128 + hf * 64 + lane];
            int d = hf * 64 + row;
            size_t off = (size_t)d * 1024 + pb * 64 + lane;
            float yv = ys[off], zv = zz[off], xcv = xc[off];
            sG[row * 68 + lane] = (yv + dpar[d] * xcv) * (zv * sigmoidf_(zv));
        }
        __syncthreads();
        for (int dl = 0; dl < 64; ++dl) {
            float4 wv = *(const float4*)&sW[dl * 68 + ct * 4];
            float4 gv = *(const float4*)&sG[dl * 68 + pt * 4];
            float w[4] = {wv.x, wv.y, wv.z, wv.w};
            float g[4] = {gv.x, gv.y, gv.z, gv.w};
#pragma unroll
            for (int i = 0; i < 4; ++i)
#pragma unroll
                for (int j = 0; j < 4; ++j) acc[i][j] += w[i] * g[j];
        }
        __syncthreads();
    }

    // epilogue: + skip * xn (recomputed from x and stored stats)
    const float* xin = (branch==0)?x0:(branch==1)?x1:(branch==2)?x2:x3;
    const float* gam = (branch==0)?g1:(branch==1)?g2:(branch==2)?g3:g4;
    const float* bet = (branch==0)?be1:(branch==1)?be2:(branch==2)?be3:be4;
    const float* xb = xin + (size_t)b * 65536;
    int p0 = pb * 64 + pt * 4;
    float skipv = skipp[0];
    float4 m4 = *(const float4*)&ws[O_M  + (size_t)seq * 1024 + p0];
    float4 r4 = *(const float4*)&ws[O_RS + (size_t)seq * 1024 + p0];
    float mm[4] = {m4.x, m4.y, m4.z, m4.w};
    float rr[4] = {r4.x, r4.y, r4.z, r4.w};
#pragma unroll
    for (int ci = 0; ci < 4; ++ci) {
        int c = ct * 4 + ci;
        float4 xv = *(const float4*)&xb[(size_t)c * 1024 + p0];
        float xvv[4] = {xv.x, xv.y, xv.z, xv.w};
        float gc = gam[c], bc = bet[c];
        float o[4];
#pragma unroll
        for (int pi = 0; pi < 4; ++pi) {
            float xn = (xvv[pi] - mm[pi]) * rr[pi] * gc + bc;
            o[pi] = acc[ci][pi] + skipv * xn;
        }
        *(float4*)&out[((size_t)b * 256 + branch * 64 + c) * 1024 + p0] =
            make_float4(o[0], o[1], o[2], o[3]);
    }
}

// ---------------- launch ----------------
extern "C" void kernel_launch(void* const* d_in, const int* in_sizes, int n_in,
                              void* d_out, int out_size, void* d_ws, size_t ws_size,
                              hipStream_t stream) {
    float* ws = (float*)d_ws;
    auto f = [&](int i) { return (const float*)d_in[i]; };
    hipLaunchKernelGGL(k1_ln_inproj, dim3(2048), dim3(256), 0, stream,
        f(0), f(1), f(2), f(3), f(13),
        f(4), f(5), f(6), f(7), f(8), f(9), f(10), f(11), ws);
    hipLaunchKernelGGL(k2_conv_proj, dim3(512), dim3(256), 0, stream,
        f(14), f(15), f(16), ws);
    hipLaunchKernelGGL(k3a_scan, dim3(1024), dim3(256), 0, stream, f(17), f(18), f(19), ws);
    hipLaunchKernelGGL(k3b_compose, dim3(32), dim3(256), 0, stream, ws);
    hipLaunchKernelGGL(k3c_scan_y, dim3(1024), dim3(256), 0, stream, f(17), f(18), f(19), ws);
    hipLaunchKernelGGL(k4_out, dim3(512), dim3(256), 0, stream,
        f(0), f(1), f(2), f(3),
        f(4), f(5), f(6), f(7), f(8), f(9), f(10), f(11),
        f(20), f(21), f(12), ws, (float*)d_out);
}

// Round 3
// 229.261 us; speedup vs baseline: 1.0693x; 1.0145x over previous
//
#include <hip/hip_runtime.h>
#include <hip/hip_bf16.h>

#define L2E 1.4426950408889634f
#define LN2 0.6931471805599453f

__device__ __forceinline__ float fexp2(float x) { return __builtin_amdgcn_exp2f(x); }
__device__ __forceinline__ float flog2(float x) { return __builtin_amdgcn_logf(x); }
__device__ __forceinline__ int uniform(int x) { return __builtin_amdgcn_readfirstlane(x); }
__device__ __forceinline__ float sigmoidf_(float v) { return 1.f / (1.f + fexp2(-v * L2E)); }
__device__ __forceinline__ float softplusf_(float t) {
    return (t > 20.f) ? t : LN2 * flog2(1.f + fexp2(t * L2E));
}

// ---------------- workspace layout (floats), total 18,022,400 = 72.1 MB ----------------
constexpr size_t O_M   = 0;          // [32][1024] LN mean
constexpr size_t O_RS  = 32768;      // [32][1024] LN rstd
constexpr size_t O_G   = 65536;      // [32][128][1024] xi
constexpr size_t O_Z   = 4259840;    // [32][128][1024] z
constexpr size_t O_XC  = 8454144;    // [32][128][1024] conv+silu out
constexpr size_t O_BM  = 12648448;   // [32][16][1024]
constexpr size_t O_CM  = 13172736;   // [32][16][1024]
constexpr size_t O_DTP = 13697024;   // [32][1024][4] dt-proj pre-softplus
constexpr size_t O_HP  = 13828096;   // [32][32][2][2048]: per-chunk P (→h_init) and E

// ================= K1: LN (in-block) + in-proj GEMM W[256,64] @ XN[64,1024] =================
// grid 2048 = 32 seq * 4 jb * 16 pb; block 256 (16 jt x 16 pt), tile 64j x 64p, K=64.
__global__ __launch_bounds__(256) void k1_ln_inproj(
    const float* __restrict__ x0, const float* __restrict__ x1,
    const float* __restrict__ x2, const float* __restrict__ x3,
    const float* __restrict__ win,
    const float* __restrict__ g1, const float* __restrict__ be1,
    const float* __restrict__ g2, const float* __restrict__ be2,
    const float* __restrict__ g3, const float* __restrict__ be3,
    const float* __restrict__ g4, const float* __restrict__ be4,
    float* __restrict__ ws)
{
    __shared__ float sX[64 * 68];
    __shared__ float sW[64 * 68];
    __shared__ float sM[64], sR[64];
    int bid = blockIdx.x;
    int seq = bid >> 6, jb = (bid >> 4) & 3, pb = bid & 15;
    int branch = seq >> 3, b = seq & 7;
    int tid = threadIdx.x;
    int lane = tid & 63;
    int wq = uniform(tid >> 6);
    const float* xin = (branch==0)?x0:(branch==1)?x1:(branch==2)?x2:x3;
    const float* gam = (branch==0)?g1:(branch==1)?g2:(branch==2)?g3:g4;
    const float* bet = (branch==0)?be1:(branch==1)?be2:(branch==2)?be3:be4;
    const float* xb = xin + (size_t)b * 65536;

#pragma unroll
    for (int r = 0; r < 16; ++r) {
        int row = r * 4 + wq;                         // uniform per wave
        sX[row * 68 + lane] = xb[(size_t)row * 1024 + pb * 64 + lane];
        sW[lane * 68 + row] = win[(size_t)(jb * 64 + row) * 64 + lane];
    }
    __syncthreads();
    if (tid < 64) {
        float sum = 0.f, sq = 0.f;
#pragma unroll
        for (int c = 0; c < 64; ++c) {
            float v = sX[c * 68 + tid];
            sum += v; sq += v * v;
        }
        float mean = sum * (1.f/64.f);
        float var  = sq * (1.f/64.f) - mean * mean;
        float rs   = rsqrtf(var + 1e-5f);
        sM[tid] = mean; sR[tid] = rs;
        if (jb == 0) {
            ws[O_M  + (size_t)seq * 1024 + pb * 64 + tid] = mean;
            ws[O_RS + (size_t)seq * 1024 + pb * 64 + tid] = rs;
        }
    }
    __syncthreads();
#pragma unroll
    for (int r = 0; r < 16; ++r) {
        int c = r * 4 + wq;
        float v = sX[c * 68 + lane];
        sX[c * 68 + lane] = (v - sM[lane]) * sR[lane] * gam[c] + bet[c];
    }
    __syncthreads();
    int jt = tid >> 4, pt = tid & 15;
    float acc[4][4];
#pragma unroll
    for (int i = 0; i < 4; ++i)
#pragma unroll
        for (int j = 0; j < 4; ++j) acc[i][j] = 0.f;
    for (int c = 0; c < 64; ++c) {
        float4 wv = *(const float4*)&sW[c * 68 + jt * 4];
        float4 xv = *(const float4*)&sX[c * 68 + pt * 4];
        float w[4] = {wv.x, wv.y, wv.z, wv.w};
        float x[4] = {xv.x, xv.y, xv.z, xv.w};
#pragma unroll
        for (int i = 0; i < 4; ++i)
#pragma unroll
            for (int j = 0; j < 4; ++j) acc[i][j] += w[i] * x[j];
    }
    int p0 = pb * 64 + pt * 4;
    float* xi = ws + O_G + (size_t)seq * 131072;
    float* zz = ws + O_Z + (size_t)seq * 131072;
#pragma unroll
    for (int ji = 0; ji < 4; ++ji) {
        int j = jb * 64 + jt * 4 + ji;
        float4 v = make_float4(acc[ji][0], acc[ji][1], acc[ji][2], acc[ji][3]);
        if (j < 128) *(float4*)&xi[(size_t)j * 1024 + p0] = v;
        else         *(float4*)&zz[(size_t)(j - 128) * 1024 + p0] = v;
    }
}

// ================= K2: conv4 + SiLU + x-proj(128->36) — all operands in LDS =================
// grid 512 = 32 seq * 16 ptile; block 256 = 4 waves x 64 p-lanes.
// Phase 3 weights: per-wave replicated LDS copies -> same-address broadcast reads
// (round-2 fix: uniform-pointer global loads did NOT scalarize; ~25 us of latency).
__global__ __launch_bounds__(256) void k2_conv_proj(
    const float* __restrict__ wconv, const float* __restrict__ bconv,
    const float* __restrict__ wxp, float* __restrict__ ws)
{
    __shared__ float sX[128 * 68];       // [d][c], c <-> p = p0-3+c
    __shared__ float sWr[4 * 128 * 12];  // per-wave replica: [wq][d][jj], jj=0..8
    int bid = blockIdx.x;
    int seq = bid >> 4, ptile = bid & 15;
    int tid = threadIdx.x;
    int lane = tid & 63;
    int wq = uniform(tid >> 6);
    int p0 = ptile * 64;
    int p  = p0 + lane;
    int j0 = wq * 9;

    const float* xirow = ws + O_G  + (size_t)seq * 131072;
    float*       xcrow = ws + O_XC + (size_t)seq * 131072;

    // ---- phase 1: stage xi tile + weight replicas ----
#pragma unroll 4
    for (int r = 0; r < 32; ++r) {
        int d = r * 4 + wq;                            // uniform per wave
        const float* row = xirow + (size_t)d * 1024;
        int gp = p0 - 3 + lane;
        sX[d * 68 + lane] = (gp >= 0) ? row[gp] : 0.f;
        if (lane < 3) sX[d * 68 + 64 + lane] = row[p0 + 61 + lane];
    }
#pragma unroll
    for (int jj = 0; jj < 9; ++jj) {
#pragma unroll
        for (int half = 0; half < 2; ++half) {
            int d = half * 64 + lane;
            sWr[(wq * 128 + d) * 12 + jj] = wxp[(size_t)(j0 + jj) * 128 + d];
        }
    }
    __syncthreads();

    // ---- phase 2: conv4 + silu (wave wq owns d rows wq*32 .. wq*32+31) ----
#pragma unroll 2
    for (int dd = 0; dd < 32; ++dd) {
        int d = wq * 32 + dd;                          // uniform
        float4 wc = *(const float4*)&wconv[d * 4];     // uniform scalar loads
        float v = bconv[d];
        float* rowl = &sX[d * 68];
        v += rowl[lane + 0] * wc.x;
        v += rowl[lane + 1] * wc.y;
        v += rowl[lane + 2] * wc.z;
        v += rowl[lane + 3] * wc.w;
        v = v * sigmoidf_(v);                          // silu
        xcrow[(size_t)d * 1024 + p] = v;               // coalesced global store
        rowl[lane + 3] = v;                            // in-place: reads above precede write
    }
    __syncthreads();

    // ---- phase 3: x-proj, K = 128; weights via LDS broadcast ----
    float acc[9];
#pragma unroll
    for (int jj = 0; jj < 9; ++jj) acc[jj] = 0.f;
#pragma unroll 4
    for (int d = 0; d < 128; ++d) {
        float xcv = sX[d * 68 + 3 + lane];             // stride-1: conflict-free
        const float* wr = &sWr[(wq * 128 + d) * 12];   // wave-uniform -> broadcast
        float4 wA = *(const float4*)wr;
        float4 wB = *(const float4*)(wr + 4);
        float  w8 = wr[8];
        acc[0] += wA.x * xcv; acc[1] += wA.y * xcv;
        acc[2] += wA.z * xcv; acc[3] += wA.w * xcv;
        acc[4] += wB.x * xcv; acc[5] += wB.y * xcv;
        acc[6] += wB.z * xcv; acc[7] += wB.w * xcv;
        acc[8] += w8 * xcv;
    }

    float* Bm = ws + O_BM + (size_t)seq * 16384;
    float* Cm = ws + O_CM + (size_t)seq * 16384;
#pragma unroll
    for (int jj = 0; jj < 9; ++jj) {
        int j = j0 + jj;
        float t = acc[jj];
        if (j < 4)       ws[O_DTP + ((size_t)seq * 1024 + p) * 4 + j] = t;
        else if (j < 20) Bm[(size_t)(j - 4)  * 1024 + p] = t;
        else             Cm[(size_t)(j - 20) * 1024 + p] = t;
    }
}

// ================= K3: chunk-parallel scan, 32 chunks of 32 steps =================
__device__ __forceinline__ void k3_preload(const float* wdt, const float* bdt,
                                           const float* alog, int d0, int s0,
                                           float4& wdt0, float4& wdt1, float& bdt0, float& bdt1,
                                           float* a2)
{
    wdt0 = *(const float4*)(wdt + d0 * 4);
    wdt1 = *(const float4*)(wdt + (d0 + 1) * 4);
    bdt0 = bdt[d0]; bdt1 = bdt[d0 + 1];
    float4 a0 = *(const float4*)(alog + d0 * 16 + s0);
    float4 a1 = *(const float4*)(alog + (d0 + 1) * 16 + s0);
    a2[0] = -fexp2(a0.x * L2E) * L2E; a2[1] = -fexp2(a0.y * L2E) * L2E;
    a2[2] = -fexp2(a0.z * L2E) * L2E; a2[3] = -fexp2(a0.w * L2E) * L2E;
    a2[4] = -fexp2(a1.x * L2E) * L2E; a2[5] = -fexp2(a1.y * L2E) * L2E;
    a2[6] = -fexp2(a1.z * L2E) * L2E; a2[7] = -fexp2(a1.w * L2E) * L2E;
}

// phase A: local scan (h0=0); emit per-chunk P = exp2(a2*sum_dt) and end-state E
__global__ __launch_bounds__(256) void k3a_scan(const float* __restrict__ wdt,
                                                const float* __restrict__ bdt,
                                                const float* __restrict__ alog,
                                                float* __restrict__ ws)
{
    __shared__ float sXC[128 * 33];
    __shared__ __align__(16) float sB[32 * 16];
    __shared__ __align__(16) float sDtp[32 * 4];
    int bid = blockIdx.x;
    int seq = bid >> 5, ch = bid & 31;
    int lb = ch * 32;
    int tid = threadIdx.x;
    int d0 = (tid >> 2) * 2, s0 = (tid & 3) * 4;

    float4 wdt0, wdt1; float bdt0, bdt1; float a2[8];
    k3_preload(wdt, bdt, alog, d0, s0, wdt0, wdt1, bdt0, bdt1, a2);

    const float* xcg = ws + O_XC + (size_t)seq * 131072;
    const float* Bmg = ws + O_BM + (size_t)seq * 16384;
    for (int i = tid; i < 4096; i += 256) {
        int d = i >> 5, li = i & 31;
        sXC[d * 33 + li] = xcg[(size_t)d * 1024 + lb + li];
    }
    for (int i = tid; i < 512; i += 256) {
        int s = i >> 5, li = i & 31;
        sB[li * 16 + s] = Bmg[(size_t)s * 1024 + lb + li];
    }
    if (tid < 128) sDtp[tid] = ws[O_DTP + ((size_t)seq * 1024 + lb + (tid >> 2)) * 4 + (tid & 3)];
    __syncthreads();

    float h[8];
#pragma unroll
    for (int i = 0; i < 8; ++i) h[i] = 0.f;
    float sdt0 = 0.f, sdt1 = 0.f;
    for (int li = 0; li < 32; ++li) {
        float4 q = *(const float4*)&sDtp[li * 4];
        float dt0 = softplusf_(bdt0 + q.x*wdt0.x + q.y*wdt0.y + q.z*wdt0.z + q.w*wdt0.w);
        float dt1 = softplusf_(bdt1 + q.x*wdt1.x + q.y*wdt1.y + q.z*wdt1.z + q.w*wdt1.w);
        float xc0 = sXC[d0 * 33 + li], xc1 = sXC[(d0 + 1) * 33 + li];
        float dx0 = dt0 * xc0, dx1 = dt1 * xc1;
        float4 Bv = *(const float4*)&sB[li * 16 + s0];
        float bv[4] = {Bv.x, Bv.y, Bv.z, Bv.w};
        sdt0 += dt0; sdt1 += dt1;
#pragma unroll
        for (int ss = 0; ss < 4; ++ss) {
            float e0 = fexp2(dt0 * a2[ss]);
            h[ss] = e0 * h[ss] + dx0 * bv[ss];
            float e1 = fexp2(dt1 * a2[4 + ss]);
            h[4 + ss] = e1 * h[4 + ss] + dx1 * bv[ss];
        }
    }
    float* hp = ws + O_HP + (size_t)(seq * 32 + ch) * 4096;
#pragma unroll
    for (int ss = 0; ss < 4; ++ss) {
        hp[d0 * 16 + s0 + ss]            = fexp2(a2[ss] * sdt0);
        hp[(d0 + 1) * 16 + s0 + ss]      = fexp2(a2[4 + ss] * sdt1);
        hp[2048 + d0 * 16 + s0 + ss]     = h[ss];
        hp[2048 + (d0 + 1) * 16 + s0 + ss] = h[4 + ss];
    }
}

// phase B: sequential prefix compose. grid 256 = 32 seq * 8 dgroups (8x TLP vs old 32),
// 1 state/thread, coalesced scalar loads, 1-deep prefetch.
__global__ __launch_bounds__(256) void k3b_compose(float* __restrict__ ws)
{
    int seq = blockIdx.x >> 3, dg = blockIdx.x & 7;
    int idx = dg * 256 + threadIdx.x;          // state index in [0,2048)
    float h = 0.f;
    float* hpb = ws + O_HP + (size_t)seq * 32 * 4096;
    float P = hpb[idx];
    float E = hpb[2048 + idx];
    for (int c = 0; c < 32; ++c) {
        float* hp = hpb + (size_t)c * 4096;
        float Pn = 0.f, En = 0.f;
        if (c < 31) { Pn = hp[4096 + idx]; En = hp[4096 + 2048 + idx]; }
        hp[idx] = h;                            // h_init overwrites P slot
        h = P * h + E;
        P = Pn; E = En;
    }
}

// ================= K3CD: rescan from h_init + gate + out-proj + skip (fused k3c+k4) =======
// grid 1024 = 32 seq * 32 ch; block 256. y never leaves LDS.
__global__ __launch_bounds__(256) void k3cd(
    const float* __restrict__ wdt, const float* __restrict__ bdt,
    const float* __restrict__ alog,
    const float* __restrict__ x0, const float* __restrict__ x1,
    const float* __restrict__ x2, const float* __restrict__ x3,
    const float* __restrict__ g1, const float* __restrict__ be1,
    const float* __restrict__ g2, const float* __restrict__ be2,
    const float* __restrict__ g3, const float* __restrict__ be3,
    const float* __restrict__ g4, const float* __restrict__ be4,
    const float* __restrict__ dpar, const float* __restrict__ woutp,
    const float* __restrict__ skipp, float* __restrict__ ws,
    float* __restrict__ out)
{
    __shared__ float sXC[128 * 33];                  // xc tile
    __shared__ __align__(16) float sY[128 * 36];     // y, then gated g
    __shared__ float sWt[128 * 66];                  // Wout^T [d][c]
    __shared__ __align__(16) float sB[32 * 16];
    __shared__ __align__(16) float sC[32 * 16];
    __shared__ __align__(16) float sDtp[32 * 4];
    int bid = blockIdx.x;
    int seq = bid >> 5, ch = bid & 31;
    int branch = seq >> 3, b = seq & 7;
    int lb = ch * 32;
    int tid = threadIdx.x;
    int sq = tid & 3;
    int d0 = (tid >> 2) * 2, s0 = sq * 4;

    float4 wdt0, wdt1; float bdt0, bdt1; float a2[8];
    k3_preload(wdt, bdt, alog, d0, s0, wdt0, wdt1, bdt0, bdt1, a2);

    const float* xcg = ws + O_XC + (size_t)seq * 131072;
    const float* Bmg = ws + O_BM + (size_t)seq * 16384;
    const float* Cmg = ws + O_CM + (size_t)seq * 16384;
    for (int i = tid; i < 4096; i += 256) {
        int d = i >> 5, li = i & 31;
        sXC[d * 33 + li] = xcg[(size_t)d * 1024 + lb + li];
    }
    for (int i = tid; i < 512; i += 256) {
        int s = i >> 5, li = i & 31;
        sB[li * 16 + s] = Bmg[(size_t)s * 1024 + lb + li];
        sC[li * 16 + s] = Cmg[(size_t)s * 1024 + lb + li];
    }
    if (tid < 128) sDtp[tid] = ws[O_DTP + ((size_t)seq * 1024 + lb + (tid >> 2)) * 4 + (tid & 3)];
    for (int i = tid; i < 64 * 128; i += 256) {      // stage Wout^T
        int c = i >> 7, d = i & 127;
        sWt[d * 66 + c] = woutp[i];
    }

    const float* hp = ws + O_HP + (size_t)(seq * 32 + ch) * 4096;
    float4 H0 = *(const float4*)&hp[d0 * 16 + s0];
    float4 H1 = *(const float4*)&hp[(d0 + 1) * 16 + s0];
    float h[8] = {H0.x, H0.y, H0.z, H0.w, H1.x, H1.y, H1.z, H1.w};
    __syncthreads();

    // ---- rescan: y into sY (stride 36) ----
    for (int li = 0; li < 32; ++li) {
        float4 q = *(const float4*)&sDtp[li * 4];
        float dt0 = softplusf_(bdt0 + q.x*wdt0.x + q.y*wdt0.y + q.z*wdt0.z + q.w*wdt0.w);
        float dt1 = softplusf_(bdt1 + q.x*wdt1.x + q.y*wdt1.y + q.z*wdt1.z + q.w*wdt1.w);
        float xc0 = sXC[d0 * 33 + li], xc1 = sXC[(d0 + 1) * 33 + li];
        float dx0 = dt0 * xc0, dx1 = dt1 * xc1;
        float4 Bv = *(const float4*)&sB[li * 16 + s0];
        float4 Cv = *(const float4*)&sC[li * 16 + s0];
        float bv[4] = {Bv.x, Bv.y, Bv.z, Bv.w};
        float cv[4] = {Cv.x, Cv.y, Cv.z, Cv.w};
        float acc0 = 0.f, acc1 = 0.f;
#pragma unroll
        for (int ss = 0; ss < 4; ++ss) {
            float e0 = fexp2(dt0 * a2[ss]);
            h[ss] = e0 * h[ss] + dx0 * bv[ss];
            acc0 += h[ss] * cv[ss];
            float e1 = fexp2(dt1 * a2[4 + ss]);
            h[4 + ss] = e1 * h[4 + ss] + dx1 * bv[ss];
            acc1 += h[4 + ss] * cv[ss];
        }
        acc0 += __shfl_xor(acc0, 1); acc0 += __shfl_xor(acc0, 2);
        acc1 += __shfl_xor(acc1, 1); acc1 += __shfl_xor(acc1, 2);
        if (sq == 0) {
            sY[d0 * 36 + li]       = acc0;
            sY[(d0 + 1) * 36 + li] = acc1;
        }
    }
    __syncthreads();

    // ---- gate in place: g = (y + D*xc) * silu(z) ----
    const float* zzg = ws + O_Z + (size_t)seq * 131072;
    for (int i = tid; i < 4096; i += 256) {
        int d = i >> 5, li = i & 31;
        float zv = zzg[(size_t)d * 1024 + lb + li];
        float yv = sY[d * 36 + li];
        float xcv = sXC[d * 33 + li];
        sY[d * 36 + li] = (yv + dpar[d] * xcv) * (zv * sigmoidf_(zv));
    }
    __syncthreads();

    // ---- out-proj GEMM: out[64c][32p] = Wout[64][128] @ g[128][32] ----
    int ctt = tid >> 3;          // 0..31 -> c0 = 2*ctt
    int ptq = tid & 7;           // p0 = 4*ptq
    int c0 = ctt * 2;
    float acc[2][4];
#pragma unroll
    for (int i = 0; i < 2; ++i)
#pragma unroll
        for (int j = 0; j < 4; ++j) acc[i][j] = 0.f;
#pragma unroll 4
    for (int d = 0; d < 128; ++d) {
        float2 wv = *(const float2*)&sWt[d * 66 + c0];
        float4 gv = *(const float4*)&sY[d * 36 + ptq * 4];
        acc[0][0] += wv.x * gv.x; acc[0][1] += wv.x * gv.y;
        acc[0][2] += wv.x * gv.z; acc[0][3] += wv.x * gv.w;
        acc[1][0] += wv.y * gv.x; acc[1][1] += wv.y * gv.y;
        acc[1][2] += wv.y * gv.z; acc[1][3] += wv.y * gv.w;
    }

    // ---- epilogue: + skip * xn ----
    const float* xin = (branch==0)?x0:(branch==1)?x1:(branch==2)?x2:x3;
    const float* gam = (branch==0)?g1:(branch==1)?g2:(branch==2)?g3:g4;
    const float* bet = (branch==0)?be1:(branch==1)?be2:(branch==2)?be3:be4;
    const float* xb = xin + (size_t)b * 65536;
    int pp = lb + ptq * 4;
    float skipv = skipp[0];
    float4 m4 = *(const float4*)&ws[O_M  + (size_t)seq * 1024 + pp];
    float4 r4 = *(const float4*)&ws[O_RS + (size_t)seq * 1024 + pp];
    float mm[4] = {m4.x, m4.y, m4.z, m4.w};
    float rr[4] = {r4.x, r4.y, r4.z, r4.w};
#pragma unroll
    for (int ci = 0; ci < 2; ++ci) {
        int c = c0 + ci;
        float4 xv = *(const float4*)&xb[(size_t)c * 1024 + pp];
        float xvv[4] = {xv.x, xv.y, xv.z, xv.w};
        float gc = gam[c], bc = bet[c];
        float o[4];
#pragma unroll
        for (int pi = 0; pi < 4; ++pi) {
            float xn = (xvv[pi] - mm[pi]) * rr[pi] * gc + bc;
            o[pi] = acc[ci][pi] + skipv * xn;
        }
        *(float4*)&out[((size_t)b * 256 + branch * 64 + c) * 1024 + pp] =
            make_float4(o[0], o[1], o[2], o[3]);
    }
}

// ---------------- launch ----------------
extern "C" void kernel_launch(void* const* d_in, const int* in_sizes, int n_in,
                              void* d_out, int out_size, void* d_ws, size_t ws_size,
                              hipStream_t stream) {
    float* ws = (float*)d_ws;
    auto f = [&](int i) { return (const float*)d_in[i]; };
    hipLaunchKernelGGL(k1_ln_inproj, dim3(2048), dim3(256), 0, stream,
        f(0), f(1), f(2), f(3), f(13),
        f(4), f(5), f(6), f(7), f(8), f(9), f(10), f(11), ws);
    hipLaunchKernelGGL(k2_conv_proj, dim3(512), dim3(256), 0, stream,
        f(14), f(15), f(16), ws);
    hipLaunchKernelGGL(k3a_scan, dim3(1024), dim3(256), 0, stream, f(17), f(18), f(19), ws);
    hipLaunchKernelGGL(k3b_compose, dim3(256), dim3(256), 0, stream, ws);
    hipLaunchKernelGGL(k3cd, dim3(1024), dim3(256), 0, stream,
        f(17), f(18), f(19),
        f(0), f(1), f(2), f(3),
        f(4), f(5), f(6), f(7), f(8), f(9), f(10), f(11),
        f(20), f(21), f(12), ws, (float*)d_out);
}

// Round 5
// 214.102 us; speedup vs baseline: 1.1450x; 1.0708x over previous
//
#include <hip/hip_runtime.h>
#include <hip/hip_bf16.h>

#define L2E 1.4426950408889634f
#define LN2 0.6931471805599453f

__device__ __forceinline__ float fexp2(float x) { return __builtin_amdgcn_exp2f(x); }
__device__ __forceinline__ float flog2(float x) { return __builtin_amdgcn_logf(x); }
__device__ __forceinline__ int uniform(int x) { return __builtin_amdgcn_readfirstlane(x); }
__device__ __forceinline__ float sigmoidf_(float v) { return 1.f / (1.f + fexp2(-v * L2E)); }
__device__ __forceinline__ float softplusf_(float t) {
    return (t > 20.f) ? t : LN2 * flog2(1.f + fexp2(t * L2E));
}

// ---------------- workspace layout (floats), total 26,411,008 = 105.6 MB (pool = 256 MiB) ----
constexpr size_t O_M   = 0;          // [32][1024] LN mean
constexpr size_t O_RS  = 32768;      // [32][1024] LN rstd
constexpr size_t O_G   = 65536;      // [32][128][1024] xi
constexpr size_t O_Z   = 4259840;    // [32][128][1024] z
constexpr size_t O_XC  = 8454144;    // [32][128][1024] conv+silu out
constexpr size_t O_BM  = 12648448;   // [32][16][1024]
constexpr size_t O_CM  = 13172736;   // [32][16][1024]
constexpr size_t O_DTP = 13697024;   // (unused now; kept for layout stability)
constexpr size_t O_HP  = 13828096;   // [32][32][2][2048]: per-chunk P (→h_init) and E
constexpr size_t O_DT  = 18022400;   // [32][128][1024] dt (post-softplus)  — NEW (k2 phase 4)
constexpr size_t O_DX  = 22216704;   // [32][128][1024] dx = dt*xc          — NEW (k2 phase 4)

// ================= K1: LN (in-block) + in-proj GEMM W[256,64] @ XN[64,1024] =================
// grid 2048 = 32 seq * 4 jb * 16 pb; block 256 (16 jt x 16 pt), tile 64j x 64p, K=64.
__global__ __launch_bounds__(256) void k1_ln_inproj(
    const float* __restrict__ x0, const float* __restrict__ x1,
    const float* __restrict__ x2, const float* __restrict__ x3,
    const float* __restrict__ win,
    const float* __restrict__ g1, const float* __restrict__ be1,
    const float* __restrict__ g2, const float* __restrict__ be2,
    const float* __restrict__ g3, const float* __restrict__ be3,
    const float* __restrict__ g4, const float* __restrict__ be4,
    float* __restrict__ ws)
{
    __shared__ float sX[64 * 68];
    __shared__ float sW[64 * 68];
    __shared__ float sM[64], sR[64];
    int bid = blockIdx.x;
    int seq = bid >> 6, jb = (bid >> 4) & 3, pb = bid & 15;
    int branch = seq >> 3, b = seq & 7;
    int tid = threadIdx.x;
    int lane = tid & 63;
    int wq = uniform(tid >> 6);
    const float* xin = (branch==0)?x0:(branch==1)?x1:(branch==2)?x2:x3;
    const float* gam = (branch==0)?g1:(branch==1)?g2:(branch==2)?g3:g4;
    const float* bet = (branch==0)?be1:(branch==1)?be2:(branch==2)?be3:be4;
    const float* xb = xin + (size_t)b * 65536;

#pragma unroll
    for (int r = 0; r < 16; ++r) {
        int row = r * 4 + wq;                         // uniform per wave
        sX[row * 68 + lane] = xb[(size_t)row * 1024 + pb * 64 + lane];
        sW[lane * 68 + row] = win[(size_t)(jb * 64 + row) * 64 + lane];
    }
    __syncthreads();
    if (tid < 64) {
        float sum = 0.f, sq = 0.f;
#pragma unroll
        for (int c = 0; c < 64; ++c) {
            float v = sX[c * 68 + tid];
            sum += v; sq += v * v;
        }
        float mean = sum * (1.f/64.f);
        float var  = sq * (1.f/64.f) - mean * mean;
        float rs   = rsqrtf(var + 1e-5f);
        sM[tid] = mean; sR[tid] = rs;
        if (jb == 0) {
            ws[O_M  + (size_t)seq * 1024 + pb * 64 + tid] = mean;
            ws[O_RS + (size_t)seq * 1024 + pb * 64 + tid] = rs;
        }
    }
    __syncthreads();
#pragma unroll
    for (int r = 0; r < 16; ++r) {
        int c = r * 4 + wq;
        float v = sX[c * 68 + lane];
        sX[c * 68 + lane] = (v - sM[lane]) * sR[lane] * gam[c] + bet[c];
    }
    __syncthreads();
    int jt = tid >> 4, pt = tid & 15;
    float acc[4][4];
#pragma unroll
    for (int i = 0; i < 4; ++i)
#pragma unroll
        for (int j = 0; j < 4; ++j) acc[i][j] = 0.f;
    for (int c = 0; c < 64; ++c) {
        float4 wv = *(const float4*)&sW[c * 68 + jt * 4];
        float4 xv = *(const float4*)&sX[c * 68 + pt * 4];
        float w[4] = {wv.x, wv.y, wv.z, wv.w};
        float x[4] = {xv.x, xv.y, xv.z, xv.w};
#pragma unroll
        for (int i = 0; i < 4; ++i)
#pragma unroll
            for (int j = 0; j < 4; ++j) acc[i][j] += w[i] * x[j];
    }
    int p0 = pb * 64 + pt * 4;
    float* xi = ws + O_G + (size_t)seq * 131072;
    float* zz = ws + O_Z + (size_t)seq * 131072;
#pragma unroll
    for (int ji = 0; ji < 4; ++ji) {
        int j = jb * 64 + jt * 4 + ji;
        float4 v = make_float4(acc[ji][0], acc[ji][1], acc[ji][2], acc[ji][3]);
        if (j < 128) *(float4*)&xi[(size_t)j * 1024 + p0] = v;
        else         *(float4*)&zz[(size_t)(j - 128) * 1024 + p0] = v;
    }
}

// ================= K2: conv4 + SiLU + x-proj(128->36) + dt/dx precompute =================
// grid 512 = 32 seq * 16 ptile; block 256 = 4 waves x 64 p-lanes.
// Phase 4 (new): dt = softplus(dtp @ Wdt^T + bdt), dx = dt*xc, stored to O_DT/O_DX so the
// scan kernels never recompute softplus (round-3: k3cd VALU-bound at 2 blocks/CU).
__global__ __launch_bounds__(256) void k2_conv_proj(
    const float* __restrict__ wconv, const float* __restrict__ bconv,
    const float* __restrict__ wxp,
    const float* __restrict__ wdt, const float* __restrict__ bdt,
    float* __restrict__ ws)
{
    __shared__ float sX[128 * 68];       // [d][c], c <-> p = p0-3+c
    __shared__ float sWr[4 * 128 * 12];  // per-wave replica: [wq][d][jj], jj=0..8
    __shared__ __align__(16) float sDtp4[64 * 4];
    int bid = blockIdx.x;
    int seq = bid >> 4, ptile = bid & 15;
    int tid = threadIdx.x;
    int lane = tid & 63;
    int wq = uniform(tid >> 6);
    int p0 = ptile * 64;
    int p  = p0 + lane;
    int j0 = wq * 9;

    const float* xirow = ws + O_G  + (size_t)seq * 131072;
    float*       xcrow = ws + O_XC + (size_t)seq * 131072;

    // ---- phase 1: stage xi tile + weight replicas ----
#pragma unroll 4
    for (int r = 0; r < 32; ++r) {
        int d = r * 4 + wq;                            // uniform per wave
        const float* row = xirow + (size_t)d * 1024;
        int gp = p0 - 3 + lane;
        sX[d * 68 + lane] = (gp >= 0) ? row[gp] : 0.f;
        if (lane < 3) sX[d * 68 + 64 + lane] = row[p0 + 61 + lane];
    }
#pragma unroll
    for (int jj = 0; jj < 9; ++jj) {
#pragma unroll
        for (int half = 0; half < 2; ++half) {
            int d = half * 64 + lane;
            sWr[(wq * 128 + d) * 12 + jj] = wxp[(size_t)(j0 + jj) * 128 + d];
        }
    }
    __syncthreads();

    // ---- phase 2: conv4 + silu ----
#pragma unroll 2
    for (int dd = 0; dd < 32; ++dd) {
        int d = wq * 32 + dd;                          // uniform
        float4 wc = *(const float4*)&wconv[d * 4];
        float v = bconv[d];
        float* rowl = &sX[d * 68];
        v += rowl[lane + 0] * wc.x;
        v += rowl[lane + 1] * wc.y;
        v += rowl[lane + 2] * wc.z;
        v += rowl[lane + 3] * wc.w;
        v = v * sigmoidf_(v);
        xcrow[(size_t)d * 1024 + p] = v;
        rowl[lane + 3] = v;                            // in-place xc
    }
    __syncthreads();

    // ---- phase 3: x-proj, K = 128; weights via LDS broadcast ----
    float acc[9];
#pragma unroll
    for (int jj = 0; jj < 9; ++jj) acc[jj] = 0.f;
#pragma unroll 4
    for (int d = 0; d < 128; ++d) {
        float xcv = sX[d * 68 + 3 + lane];
        const float* wr = &sWr[(wq * 128 + d) * 12];
        float4 wA = *(const float4*)wr;
        float4 wB = *(const float4*)(wr + 4);
        float  w8 = wr[8];
        acc[0] += wA.x * xcv; acc[1] += wA.y * xcv;
        acc[2] += wA.z * xcv; acc[3] += wA.w * xcv;
        acc[4] += wB.x * xcv; acc[5] += wB.y * xcv;
        acc[6] += wB.z * xcv; acc[7] += wB.w * xcv;
        acc[8] += w8 * xcv;
    }

    float* Bm = ws + O_BM + (size_t)seq * 16384;
    float* Cm = ws + O_CM + (size_t)seq * 16384;
#pragma unroll
    for (int jj = 0; jj < 9; ++jj) {
        int j = j0 + jj;
        if (j < 4) continue;                           // dtp consumed in phase 4
        float t = acc[jj];
        if (j < 20) Bm[(size_t)(j - 4)  * 1024 + p] = t;
        else        Cm[(size_t)(j - 20) * 1024 + p] = t;
    }

    // ---- phase 4: dt + dx ----
    if (wq == 0)
        *(float4*)&sDtp4[lane * 4] = make_float4(acc[0], acc[1], acc[2], acc[3]);
    __syncthreads();
    float* dtg = ws + O_DT + (size_t)seq * 131072;
    float* dxg = ws + O_DX + (size_t)seq * 131072;
    float4 qv = *(const float4*)&sDtp4[lane * 4];
#pragma unroll 4
    for (int dd = 0; dd < 32; ++dd) {
        int d = wq * 32 + dd;                          // uniform
        float4 wv = *(const float4*)&wdt[d * 4];       // uniform scalar loads
        float t = bdt[d] + qv.x*wv.x + qv.y*wv.y + qv.z*wv.z + qv.w*wv.w;
        float dt = softplusf_(t);
        float dx = dt * sX[d * 68 + 3 + lane];
        dtg[(size_t)d * 1024 + p] = dt;
        dxg[(size_t)d * 1024 + p] = dx;
    }
}

// ---------------- a2 preload (A coefficients in exp2 domain) ----------------
__device__ __forceinline__ void a2_preload(const float* alog, int d0, int s0, float* a2)
{
    float4 a0 = *(const float4*)(alog + d0 * 16 + s0);
    float4 a1 = *(const float4*)(alog + (d0 + 1) * 16 + s0);
    a2[0] = -fexp2(a0.x * L2E) * L2E; a2[1] = -fexp2(a0.y * L2E) * L2E;
    a2[2] = -fexp2(a0.z * L2E) * L2E; a2[3] = -fexp2(a0.w * L2E) * L2E;
    a2[4] = -fexp2(a1.x * L2E) * L2E; a2[5] = -fexp2(a1.y * L2E) * L2E;
    a2[6] = -fexp2(a1.z * L2E) * L2E; a2[7] = -fexp2(a1.w * L2E) * L2E;
}

// ================= K3A: local scan (h0=0); emit per-chunk P and E =================
// grid 1024 = 32 seq * 32 ch; block 256; thread -> d-pair, s-quad. dt/dx from K2 (no softplus).
__global__ __launch_bounds__(256) void k3a_scan(const float* __restrict__ alog,
                                                float* __restrict__ ws)
{
    __shared__ __align__(16) float sB[32 * 16];
    int bid = blockIdx.x;
    int seq = bid >> 5, ch = bid & 31;
    int lb = ch * 32;
    int tid = threadIdx.x;
    int d0 = (tid >> 2) * 2, s0 = (tid & 3) * 4;

    float a2[8];
    a2_preload(alog, d0, s0, a2);

    const float* Bmg = ws + O_BM + (size_t)seq * 16384;
    for (int i = tid; i < 512; i += 256) {
        int s = i >> 5, li = i & 31;
        sB[li * 16 + s] = Bmg[(size_t)s * 1024 + lb + li];
    }
    __syncthreads();

    const float* r0t = ws + O_DT + (size_t)seq * 131072 + (size_t)d0 * 1024 + lb;
    const float* r1t = r0t + 1024;
    const float* r0x = ws + O_DX + (size_t)seq * 131072 + (size_t)d0 * 1024 + lb;
    const float* r1x = r0x + 1024;

    float h[8];
#pragma unroll
    for (int i = 0; i < 8; ++i) h[i] = 0.f;
    float sdt0 = 0.f, sdt1 = 0.f;
    for (int q4 = 0; q4 < 8; ++q4) {
        float4 t0 = *(const float4*)&r0t[q4 * 4];
        float4 t1 = *(const float4*)&r1t[q4 * 4];
        float4 x0 = *(const float4*)&r0x[q4 * 4];
        float4 x1 = *(const float4*)&r1x[q4 * 4];
        float t0a[4] = {t0.x, t0.y, t0.z, t0.w};
        float t1a[4] = {t1.x, t1.y, t1.z, t1.w};
        float x0a[4] = {x0.x, x0.y, x0.z, x0.w};
        float x1a[4] = {x1.x, x1.y, x1.z, x1.w};
#pragma unroll
        for (int k = 0; k < 4; ++k) {
            int li = q4 * 4 + k;
            float dt0 = t0a[k], dt1 = t1a[k];
            float dx0 = x0a[k], dx1 = x1a[k];
            float4 Bv = *(const float4*)&sB[li * 16 + s0];
            float bv[4] = {Bv.x, Bv.y, Bv.z, Bv.w};
            sdt0 += dt0; sdt1 += dt1;
#pragma unroll
            for (int ss = 0; ss < 4; ++ss) {
                float e0 = fexp2(dt0 * a2[ss]);
                h[ss] = e0 * h[ss] + dx0 * bv[ss];
                float e1 = fexp2(dt1 * a2[4 + ss]);
                h[4 + ss] = e1 * h[4 + ss] + dx1 * bv[ss];
            }
        }
    }
    float* hp = ws + O_HP + (size_t)(seq * 32 + ch) * 4096;
#pragma unroll
    for (int ss = 0; ss < 4; ++ss) {
        hp[d0 * 16 + s0 + ss]              = fexp2(a2[ss] * sdt0);
        hp[(d0 + 1) * 16 + s0 + ss]        = fexp2(a2[4 + ss] * sdt1);
        hp[2048 + d0 * 16 + s0 + ss]       = h[ss];
        hp[2048 + (d0 + 1) * 16 + s0 + ss] = h[4 + ss];
    }
}

// phase B: sequential prefix compose. grid 256 = 32 seq * 8 dgroups, 1 state/thread.
__global__ __launch_bounds__(256) void k3b_compose(float* __restrict__ ws)
{
    int seq = blockIdx.x >> 3, dg = blockIdx.x & 7;
    int idx = dg * 256 + threadIdx.x;
    float h = 0.f;
    float* hpb = ws + O_HP + (size_t)seq * 32 * 4096;
    float P = hpb[idx];
    float E = hpb[2048 + idx];
    for (int c = 0; c < 32; ++c) {
        float* hp = hpb + (size_t)c * 4096;
        float Pn = 0.f, En = 0.f;
        if (c < 31) { Pn = hp[4096 + idx]; En = hp[4096 + 2048 + idx]; }
        hp[idx] = h;
        h = P * h + E;
        P = Pn; E = En;
    }
}

// ================= K3CD: rescan + gate + out-proj + skip (slim LDS, 4 blocks/CU) =========
// grid 1024 = 32 seq * 32 ch; block 256. LDS = sY + sB + sC = 22.5 KB (was 73.7).
__global__ __launch_bounds__(256) void k3cd(
    const float* __restrict__ alog,
    const float* __restrict__ x0, const float* __restrict__ x1,
    const float* __restrict__ x2, const float* __restrict__ x3,
    const float* __restrict__ g1, const float* __restrict__ be1,
    const float* __restrict__ g2, const float* __restrict__ be2,
    const float* __restrict__ g3, const float* __restrict__ be3,
    const float* __restrict__ g4, const float* __restrict__ be4,
    const float* __restrict__ dpar, const float* __restrict__ woutp,
    const float* __restrict__ skipp, float* __restrict__ ws,
    float* __restrict__ out)
{
    __shared__ __align__(16) float sY[128 * 36];     // y, then gated g
    __shared__ __align__(16) float sB[32 * 16];
    __shared__ __align__(16) float sC[32 * 16];
    int bid = blockIdx.x;
    int seq = bid >> 5, ch = bid & 31;
    int branch = seq >> 3, b = seq & 7;
    int lb = ch * 32;
    int tid = threadIdx.x;
    int sq = tid & 3;
    int d0 = (tid >> 2) * 2, s0 = sq * 4;

    float a2[8];
    a2_preload(alog, d0, s0, a2);

    const float* Bmg = ws + O_BM + (size_t)seq * 16384;
    const float* Cmg = ws + O_CM + (size_t)seq * 16384;
    for (int i = tid; i < 512; i += 256) {
        int s = i >> 5, li = i & 31;
        sB[li * 16 + s] = Bmg[(size_t)s * 1024 + lb + li];
        sC[li * 16 + s] = Cmg[(size_t)s * 1024 + lb + li];
    }

    const float* hp = ws + O_HP + (size_t)(seq * 32 + ch) * 4096;
    float4 H0 = *(const float4*)&hp[d0 * 16 + s0];
    float4 H1 = *(const float4*)&hp[(d0 + 1) * 16 + s0];
    float h[8] = {H0.x, H0.y, H0.z, H0.w, H1.x, H1.y, H1.z, H1.w};
    __syncthreads();

    const float* r0t = ws + O_DT + (size_t)seq * 131072 + (size_t)d0 * 1024 + lb;
    const float* r1t = r0t + 1024;
    const float* r0x = ws + O_DX + (size_t)seq * 131072 + (size_t)d0 * 1024 + lb;
    const float* r1x = r0x + 1024;

    // ---- rescan: y into sY (stride 36) ----
    for (int q4 = 0; q4 < 8; ++q4) {
        float4 t0 = *(const float4*)&r0t[q4 * 4];
        float4 t1 = *(const float4*)&r1t[q4 * 4];
        float4 x0v = *(const float4*)&r0x[q4 * 4];
        float4 x1v = *(const float4*)&r1x[q4 * 4];
        float t0a[4] = {t0.x, t0.y, t0.z, t0.w};
        float t1a[4] = {t1.x, t1.y, t1.z, t1.w};
        float x0a[4] = {x0v.x, x0v.y, x0v.z, x0v.w};
        float x1a[4] = {x1v.x, x1v.y, x1v.z, x1v.w};
#pragma unroll
        for (int k = 0; k < 4; ++k) {
            int li = q4 * 4 + k;
            float dt0 = t0a[k], dt1 = t1a[k];
            float dx0 = x0a[k], dx1 = x1a[k];
            float4 Bv = *(const float4*)&sB[li * 16 + s0];
            float4 Cv = *(const float4*)&sC[li * 16 + s0];
            float bv[4] = {Bv.x, Bv.y, Bv.z, Bv.w};
            float cv[4] = {Cv.x, Cv.y, Cv.z, Cv.w};
            float acc0 = 0.f, acc1 = 0.f;
#pragma unroll
            for (int ss = 0; ss < 4; ++ss) {
                float e0 = fexp2(dt0 * a2[ss]);
                h[ss] = e0 * h[ss] + dx0 * bv[ss];
                acc0 += h[ss] * cv[ss];
                float e1 = fexp2(dt1 * a2[4 + ss]);
                h[4 + ss] = e1 * h[4 + ss] + dx1 * bv[ss];
                acc1 += h[4 + ss] * cv[ss];
            }
            acc0 += __shfl_xor(acc0, 1); acc0 += __shfl_xor(acc0, 2);
            acc1 += __shfl_xor(acc1, 1); acc1 += __shfl_xor(acc1, 2);
            if (sq == 0) {
                sY[d0 * 36 + li]       = acc0;
                sY[(d0 + 1) * 36 + li] = acc1;
            }
        }
    }
    __syncthreads();

    // ---- gate in place: g = (y + D*xc) * silu(z); xc,z direct from global (L2/L3-hot) ----
    const float* zzg = ws + O_Z  + (size_t)seq * 131072;
    const float* xcg = ws + O_XC + (size_t)seq * 131072;
    for (int i = tid; i < 4096; i += 256) {
        int d = i >> 5, li = i & 31;
        float zv  = zzg[(size_t)d * 1024 + lb + li];
        float xcv = xcg[(size_t)d * 1024 + lb + li];
        float yv  = sY[d * 36 + li];
        sY[d * 36 + li] = (yv + dpar[d] * xcv) * (zv * sigmoidf_(zv));
    }
    __syncthreads();

    // ---- out-proj GEMM: out[64c][32p] = Wout[64][128] @ g[128][32]; Wout from global (L1-hot) ----
    int ctt = tid >> 3;          // c0 = 2*ctt
    int ptq = tid & 7;           // p0 = 4*ptq
    int c0 = ctt * 2;
    const float* w0p = woutp + (size_t)c0 * 128;
    const float* w1p = w0p + 128;
    float acc[2][4];
#pragma unroll
    for (int i = 0; i < 2; ++i)
#pragma unroll
        for (int j = 0; j < 4; ++j) acc[i][j] = 0.f;
    for (int d4 = 0; d4 < 32; ++d4) {
        float4 wa = *(const float4*)&w0p[d4 * 4];
        float4 wb = *(const float4*)&w1p[d4 * 4];
        float waa[4] = {wa.x, wa.y, wa.z, wa.w};
        float wba[4] = {wb.x, wb.y, wb.z, wb.w};
#pragma unroll
        for (int k = 0; k < 4; ++k) {
            int d = d4 * 4 + k;
            float4 gv = *(const float4*)&sY[d * 36 + ptq * 4];
            acc[0][0] += waa[k] * gv.x; acc[0][1] += waa[k] * gv.y;
            acc[0][2] += waa[k] * gv.z; acc[0][3] += waa[k] * gv.w;
            acc[1][0] += wba[k] * gv.x; acc[1][1] += wba[k] * gv.y;
            acc[1][2] += wba[k] * gv.z; acc[1][3] += wba[k] * gv.w;
        }
    }

    // ---- epilogue: + skip * xn ----
    const float* xin = (branch==0)?x0:(branch==1)?x1:(branch==2)?x2:x3;
    const float* gam = (branch==0)?g1:(branch==1)?g2:(branch==2)?g3:g4;
    const float* bet = (branch==0)?be1:(branch==1)?be2:(branch==2)?be3:be4;
    const float* xb = xin + (size_t)b * 65536;
    int pp = lb + ptq * 4;
    float skipv = skipp[0];
    float4 m4 = *(const float4*)&ws[O_M  + (size_t)seq * 1024 + pp];
    float4 r4 = *(const float4*)&ws[O_RS + (size_t)seq * 1024 + pp];
    float mm[4] = {m4.x, m4.y, m4.z, m4.w};
    float rr[4] = {r4.x, r4.y, r4.z, r4.w};
#pragma unroll
    for (int ci = 0; ci < 2; ++ci) {
        int c = c0 + ci;
        float4 xv = *(const float4*)&xb[(size_t)c * 1024 + pp];
        float xvv[4] = {xv.x, xv.y, xv.z, xv.w};
        float gc = gam[c], bc = bet[c];
        float o[4];
#pragma unroll
        for (int pi = 0; pi < 4; ++pi) {
            float xn = (xvv[pi] - mm[pi]) * rr[pi] * gc + bc;
            o[pi] = acc[ci][pi] + skipv * xn;
        }
        *(float4*)&out[((size_t)b * 256 + branch * 64 + c) * 1024 + pp] =
            make_float4(o[0], o[1], o[2], o[3]);
    }
}

// ---------------- launch ----------------
extern "C" void kernel_launch(void* const* d_in, const int* in_sizes, int n_in,
                              void* d_out, int out_size, void* d_ws, size_t ws_size,
                              hipStream_t stream) {
    float* ws = (float*)d_ws;
    auto f = [&](int i) { return (const float*)d_in[i]; };
    hipLaunchKernelGGL(k1_ln_inproj, dim3(2048), dim3(256), 0, stream,
        f(0), f(1), f(2), f(3), f(13),
        f(4), f(5), f(6), f(7), f(8), f(9), f(10), f(11), ws);
    hipLaunchKernelGGL(k2_conv_proj, dim3(512), dim3(256), 0, stream,
        f(14), f(15), f(16), f(17), f(18), ws);
    hipLaunchKernelGGL(k3a_scan, dim3(1024), dim3(256), 0, stream, f(19), ws);
    hipLaunchKernelGGL(k3b_compose, dim3(256), dim3(256), 0, stream, ws);
    hipLaunchKernelGGL(k3cd, dim3(1024), dim3(256), 0, stream,
        f(19),
        f(0), f(1), f(2), f(3),
        f(4), f(5), f(6), f(7), f(8), f(9), f(10), f(11),
        f(20), f(21), f(12), ws, (float*)d_out);
}

// Round 6
// 203.541 us; speedup vs baseline: 1.2044x; 1.0519x over previous
//
#include <hip/hip_runtime.h>
#include <hip/hip_bf16.h>

#define L2E 1.4426950408889634f
#define LN2 0.6931471805599453f

__device__ __forceinline__ float fexp2(float x) { return __builtin_amdgcn_exp2f(x); }
__device__ __forceinline__ float flog2(float x) { return __builtin_amdgcn_logf(x); }
__device__ __forceinline__ int uniform(int x) { return __builtin_amdgcn_readfirstlane(x); }
__device__ __forceinline__ float sigmoidf_(float v) { return 1.f / (1.f + fexp2(-v * L2E)); }
__device__ __forceinline__ float softplusf_(float t) {
    return (t > 20.f) ? t : LN2 * flog2(1.f + fexp2(t * L2E));
}

// ---------------- workspace layout (floats), total 26,411,008 = 105.6 MB (pool = 256 MiB) ----
constexpr size_t O_M   = 0;          // [32][1024] LN mean
constexpr size_t O_RS  = 32768;      // [32][1024] LN rstd
constexpr size_t O_G   = 65536;      // [32][128][1024] xi
constexpr size_t O_Z   = 4259840;    // [32][128][1024] z
constexpr size_t O_XC  = 8454144;    // [32][128][1024] conv+silu out
constexpr size_t O_BM  = 12648448;   // [32][16][1024]
constexpr size_t O_CM  = 13172736;   // [32][16][1024]
constexpr size_t O_HP  = 13828096;   // [32][32][2][2048]: per-chunk P (→h_init) and E
constexpr size_t O_DT  = 18022400;   // [32][128][1024] dt (post-softplus)
constexpr size_t O_DX  = 22216704;   // [32][128][1024] dx = dt*xc

// ================= K1: LN + in-proj GEMM W[256,64] @ XN[64,1024], jb-merged =================
// grid 512 = 32 seq * 16 pb; block 256 (16 jt x 16 pt). X staged + LN computed ONCE,
// W tile re-staged per jb (4x). Round-5 fix: old grid 2048 re-staged X and redid LN 4x.
__global__ __launch_bounds__(256) void k1_ln_inproj(
    const float* __restrict__ x0, const float* __restrict__ x1,
    const float* __restrict__ x2, const float* __restrict__ x3,
    const float* __restrict__ win,
    const float* __restrict__ g1, const float* __restrict__ be1,
    const float* __restrict__ g2, const float* __restrict__ be2,
    const float* __restrict__ g3, const float* __restrict__ be3,
    const float* __restrict__ g4, const float* __restrict__ be4,
    float* __restrict__ ws)
{
    __shared__ float sX[64 * 68];
    __shared__ float sW[64 * 68];
    __shared__ float sM[64], sR[64];
    int bid = blockIdx.x;
    int seq = bid >> 4, pb = bid & 15;
    int branch = seq >> 3, b = seq & 7;
    int tid = threadIdx.x;
    int lane = tid & 63;
    int wq = uniform(tid >> 6);
    const float* xin = (branch==0)?x0:(branch==1)?x1:(branch==2)?x2:x3;
    const float* gam = (branch==0)?g1:(branch==1)?g2:(branch==2)?g3:g4;
    const float* bet = (branch==0)?be1:(branch==1)?be2:(branch==2)?be3:be4;
    const float* xb = xin + (size_t)b * 65536;

    // stage raw X tile [c][p]
#pragma unroll
    for (int r = 0; r < 16; ++r) {
        int row = r * 4 + wq;                         // uniform per wave
        sX[row * 68 + lane] = xb[(size_t)row * 1024 + pb * 64 + lane];
    }
    __syncthreads();
    // per-p LN stats (wave 0), stored once
    if (tid < 64) {
        float sum = 0.f, sq = 0.f;
#pragma unroll
        for (int c = 0; c < 64; ++c) {
            float v = sX[c * 68 + tid];
            sum += v; sq += v * v;
        }
        float mean = sum * (1.f/64.f);
        float var  = sq * (1.f/64.f) - mean * mean;
        float rs   = rsqrtf(var + 1e-5f);
        sM[tid] = mean; sR[tid] = rs;
        ws[O_M  + (size_t)seq * 1024 + pb * 64 + tid] = mean;
        ws[O_RS + (size_t)seq * 1024 + pb * 64 + tid] = rs;
    }
    __syncthreads();
    // normalize in LDS
#pragma unroll
    for (int r = 0; r < 16; ++r) {
        int c = r * 4 + wq;
        float v = sX[c * 68 + lane];
        sX[c * 68 + lane] = (v - sM[lane]) * sR[lane] * gam[c] + bet[c];
    }
    __syncthreads();

    int jt = tid >> 4, pt = tid & 15;
    int p0 = pb * 64 + pt * 4;
    float* xi = ws + O_G + (size_t)seq * 131072;
    float* zz = ws + O_Z + (size_t)seq * 131072;

    for (int jb = 0; jb < 4; ++jb) {
        // stage W^T tile [c][j] for this jb
#pragma unroll
        for (int r = 0; r < 16; ++r) {
            int row = r * 4 + wq;
            sW[lane * 68 + row] = win[(size_t)(jb * 64 + row) * 64 + lane];
        }
        __syncthreads();
        float acc[4][4];
#pragma unroll
        for (int i = 0; i < 4; ++i)
#pragma unroll
            for (int j = 0; j < 4; ++j) acc[i][j] = 0.f;
        for (int c = 0; c < 64; ++c) {
            float4 wv = *(const float4*)&sW[c * 68 + jt * 4];
            float4 xv = *(const float4*)&sX[c * 68 + pt * 4];
            float w[4] = {wv.x, wv.y, wv.z, wv.w};
            float x[4] = {xv.x, xv.y, xv.z, xv.w};
#pragma unroll
            for (int i = 0; i < 4; ++i)
#pragma unroll
                for (int j = 0; j < 4; ++j) acc[i][j] += w[i] * x[j];
        }
#pragma unroll
        for (int ji = 0; ji < 4; ++ji) {
            int j = jb * 64 + jt * 4 + ji;
            float4 v = make_float4(acc[ji][0], acc[ji][1], acc[ji][2], acc[ji][3]);
            if (j < 128) *(float4*)&xi[(size_t)j * 1024 + p0] = v;
            else         *(float4*)&zz[(size_t)(j - 128) * 1024 + p0] = v;
        }
        __syncthreads();   // before re-staging sW
    }
}

// ================= K2: conv4 + SiLU + x-proj + dt/dx + chunk-local scan (fused k3a) =======
// grid 512 = 32 seq * 16 ptile; block 256 = 4 waves x 64 p-lanes. Each block covers 2 chunks.
// Phase 5 (new, was k3a): dt/dx handed off via LDS; P/E written to O_HP. Kills the k3a
// launch + its 32 MB of L2 re-reads.
__global__ __launch_bounds__(256) void k2_conv_proj(
    const float* __restrict__ wconv, const float* __restrict__ bconv,
    const float* __restrict__ wxp,
    const float* __restrict__ wdt, const float* __restrict__ bdt,
    const float* __restrict__ alog,
    float* __restrict__ ws)
{
    // buf: [0,8704) sX [128][68] (xi -> xc at col 3+lane -> dx at col lane)
    //      [8704,17408) sWr (4*128*12, phases 1-3) overlaid by sDt [128][68] (phases 4-5)
    __shared__ float buf[17408];
    __shared__ __align__(16) float sDtp4[64 * 4];
    __shared__ float sB5[64 * 20];       // B rows [p][s] stride 20 (16B-aligned float4 reads)
    float* sX  = buf;
    float* sWr = buf + 8704;
    float* sDt = buf + 8704;

    int bid = blockIdx.x;
    int seq = bid >> 4, ptile = bid & 15;
    int tid = threadIdx.x;
    int lane = tid & 63;
    int wq = uniform(tid >> 6);
    int p0 = ptile * 64;
    int p  = p0 + lane;
    int j0 = wq * 9;

    const float* xirow = ws + O_G  + (size_t)seq * 131072;
    float*       xcrow = ws + O_XC + (size_t)seq * 131072;

    // ---- phase 1: stage xi tile + weight replicas ----
#pragma unroll 4
    for (int r = 0; r < 32; ++r) {
        int d = r * 4 + wq;                            // uniform per wave
        const float* row = xirow + (size_t)d * 1024;
        int gp = p0 - 3 + lane;
        sX[d * 68 + lane] = (gp >= 0) ? row[gp] : 0.f;
        if (lane < 3) sX[d * 68 + 64 + lane] = row[p0 + 61 + lane];
    }
#pragma unroll
    for (int jj = 0; jj < 9; ++jj) {
#pragma unroll
        for (int half = 0; half < 2; ++half) {
            int d = half * 64 + lane;
            sWr[(wq * 128 + d) * 12 + jj] = wxp[(size_t)(j0 + jj) * 128 + d];
        }
    }
    __syncthreads();

    // ---- phase 2: conv4 + silu ----
#pragma unroll 2
    for (int dd = 0; dd < 32; ++dd) {
        int d = wq * 32 + dd;                          // uniform
        float4 wc = *(const float4*)&wconv[d * 4];
        float v = bconv[d];
        float* rowl = &sX[d * 68];
        v += rowl[lane + 0] * wc.x;
        v += rowl[lane + 1] * wc.y;
        v += rowl[lane + 2] * wc.z;
        v += rowl[lane + 3] * wc.w;
        v = v * sigmoidf_(v);
        xcrow[(size_t)d * 1024 + p] = v;
        rowl[lane + 3] = v;                            // in-place xc
    }
    __syncthreads();

    // ---- phase 3: x-proj, K = 128; weights via LDS broadcast ----
    float acc[9];
#pragma unroll
    for (int jj = 0; jj < 9; ++jj) acc[jj] = 0.f;
#pragma unroll 4
    for (int d = 0; d < 128; ++d) {
        float xcv = sX[d * 68 + 3 + lane];
        const float* wr = &sWr[(wq * 128 + d) * 12];
        float4 wA = *(const float4*)wr;
        float4 wB = *(const float4*)(wr + 4);
        float  w8 = wr[8];
        acc[0] += wA.x * xcv; acc[1] += wA.y * xcv;
        acc[2] += wA.z * xcv; acc[3] += wA.w * xcv;
        acc[4] += wB.x * xcv; acc[5] += wB.y * xcv;
        acc[6] += wB.z * xcv; acc[7] += wB.w * xcv;
        acc[8] += w8 * xcv;
    }

    float* Bm = ws + O_BM + (size_t)seq * 16384;
    float* Cm = ws + O_CM + (size_t)seq * 16384;
#pragma unroll
    for (int jj = 0; jj < 9; ++jj) {
        int j = j0 + jj;
        if (j < 4) continue;                           // dtp consumed in phase 4
        float t = acc[jj];
        if (j < 20) { Bm[(size_t)(j - 4) * 1024 + p] = t; sB5[lane * 20 + (j - 4)] = t; }
        else        Cm[(size_t)(j - 20) * 1024 + p] = t;
    }
    if (wq == 0)
        *(float4*)&sDtp4[lane * 4] = make_float4(acc[0], acc[1], acc[2], acc[3]);
    __syncthreads();   // sWr dead; sDtp4/sB5 ready; all phase-3 sX reads done

    // ---- phase 4: dt + dx (global + LDS handoff) ----
    float* dtg = ws + O_DT + (size_t)seq * 131072;
    float* dxg = ws + O_DX + (size_t)seq * 131072;
    float4 qv = *(const float4*)&sDtp4[lane * 4];
#pragma unroll 4
    for (int dd = 0; dd < 32; ++dd) {
        int d = wq * 32 + dd;                          // uniform
        float4 wv = *(const float4*)&wdt[d * 4];       // uniform scalar loads
        float t = bdt[d] + qv.x*wv.x + qv.y*wv.y + qv.z*wv.z + qv.w*wv.w;
        float dt = softplusf_(t);
        float xc = sX[d * 68 + 3 + lane];
        float dx = dt * xc;
        dtg[(size_t)d * 1024 + p] = dt;
        dxg[(size_t)d * 1024 + p] = dx;
        sDt[d * 68 + lane] = dt;
        sX [d * 68 + lane] = dx;   // safe: dx data-depends on the xc ds_read -> ordered
    }
    __syncthreads();

    // ---- phase 5 (was k3a): chunk-local scan, h0=0; emit P and E ----
    {
        int dA = tid >> 2;           // 0..63 ; pair with dA+64 (stride-68 rows -> 2-way free)
        int dB = dA + 64;
        int s05 = (tid & 3) * 4;
        float a2[8];
        {
            float4 a0 = *(const float4*)(alog + dA * 16 + s05);
            float4 a1 = *(const float4*)(alog + dB * 16 + s05);
            a2[0] = -fexp2(a0.x * L2E) * L2E; a2[1] = -fexp2(a0.y * L2E) * L2E;
            a2[2] = -fexp2(a0.z * L2E) * L2E; a2[3] = -fexp2(a0.w * L2E) * L2E;
            a2[4] = -fexp2(a1.x * L2E) * L2E; a2[5] = -fexp2(a1.y * L2E) * L2E;
            a2[6] = -fexp2(a1.z * L2E) * L2E; a2[7] = -fexp2(a1.w * L2E) * L2E;
        }
        float* hp0 = ws + O_HP + (size_t)(seq * 32 + ptile * 2) * 4096;
#pragma unroll
        for (int cc = 0; cc < 2; ++cc) {
            const float* dtA = &sDt[dA * 68 + cc * 32];
            const float* dtB = &sDt[dB * 68 + cc * 32];
            const float* dxA = &sX [dA * 68 + cc * 32];
            const float* dxB = &sX [dB * 68 + cc * 32];
            float h[8];
#pragma unroll
            for (int i = 0; i < 8; ++i) h[i] = 0.f;
            float sdtA = 0.f, sdtB = 0.f;
            for (int q4 = 0; q4 < 8; ++q4) {
                float4 t0 = *(const float4*)&dtA[q4 * 4];
                float4 t1 = *(const float4*)&dtB[q4 * 4];
                float4 x0 = *(const float4*)&dxA[q4 * 4];
                float4 x1 = *(const float4*)&dxB[q4 * 4];
                float t0a[4] = {t0.x, t0.y, t0.z, t0.w};
                float t1a[4] = {t1.x, t1.y, t1.z, t1.w};
                float x0a[4] = {x0.x, x0.y, x0.z, x0.w};
                float x1a[4] = {x1.x, x1.y, x1.z, x1.w};
#pragma unroll
                for (int k = 0; k < 4; ++k) {
                    int li = q4 * 4 + k;
                    float4 Bv = *(const float4*)&sB5[(cc * 32 + li) * 20 + s05];
                    float bv[4] = {Bv.x, Bv.y, Bv.z, Bv.w};
                    float dt0 = t0a[k], dt1 = t1a[k];
                    float dx0 = x0a[k], dx1 = x1a[k];
                    sdtA += dt0; sdtB += dt1;
#pragma unroll
                    for (int ss = 0; ss < 4; ++ss) {
                        float e0 = fexp2(dt0 * a2[ss]);
                        h[ss] = e0 * h[ss] + dx0 * bv[ss];
                        float e1 = fexp2(dt1 * a2[4 + ss]);
                        h[4 + ss] = e1 * h[4 + ss] + dx1 * bv[ss];
                    }
                }
            }
            float* hp = hp0 + cc * 4096;
            *(float4*)&hp[dA * 16 + s05] = make_float4(
                fexp2(a2[0] * sdtA), fexp2(a2[1] * sdtA),
                fexp2(a2[2] * sdtA), fexp2(a2[3] * sdtA));
            *(float4*)&hp[dB * 16 + s05] = make_float4(
                fexp2(a2[4] * sdtB), fexp2(a2[5] * sdtB),
                fexp2(a2[6] * sdtB), fexp2(a2[7] * sdtB));
            *(float4*)&hp[2048 + dA * 16 + s05] = make_float4(h[0], h[1], h[2], h[3]);
            *(float4*)&hp[2048 + dB * 16 + s05] = make_float4(h[4], h[5], h[6], h[7]);
        }
    }
}

// ---------------- a2 preload for k3cd (d0, d0+1 pairing) ----------------
__device__ __forceinline__ void a2_preload(const float* alog, int d0, int s0, float* a2)
{
    float4 a0 = *(const float4*)(alog + d0 * 16 + s0);
    float4 a1 = *(const float4*)(alog + (d0 + 1) * 16 + s0);
    a2[0] = -fexp2(a0.x * L2E) * L2E; a2[1] = -fexp2(a0.y * L2E) * L2E;
    a2[2] = -fexp2(a0.z * L2E) * L2E; a2[3] = -fexp2(a0.w * L2E) * L2E;
    a2[4] = -fexp2(a1.x * L2E) * L2E; a2[5] = -fexp2(a1.y * L2E) * L2E;
    a2[6] = -fexp2(a1.z * L2E) * L2E; a2[7] = -fexp2(a1.w * L2E) * L2E;
}

// phase B: sequential prefix compose. grid 256 = 32 seq * 8 dgroups, 1 state/thread.
__global__ __launch_bounds__(256) void k3b_compose(float* __restrict__ ws)
{
    int seq = blockIdx.x >> 3, dg = blockIdx.x & 7;
    int idx = dg * 256 + threadIdx.x;
    float h = 0.f;
    float* hpb = ws + O_HP + (size_t)seq * 32 * 4096;
    float P = hpb[idx];
    float E = hpb[2048 + idx];
    for (int c = 0; c < 32; ++c) {
        float* hp = hpb + (size_t)c * 4096;
        float Pn = 0.f, En = 0.f;
        if (c < 31) { Pn = hp[4096 + idx]; En = hp[4096 + 2048 + idx]; }
        hp[idx] = h;
        h = P * h + E;
        P = Pn; E = En;
    }
}

// ================= K3CD: rescan + gate + out-proj + skip =================
// grid 1024 = 32 seq * 32 ch; block 256. LDS 22.5 KB.
__global__ __launch_bounds__(256) void k3cd(
    const float* __restrict__ alog,
    const float* __restrict__ x0, const float* __restrict__ x1,
    const float* __restrict__ x2, const float* __restrict__ x3,
    const float* __restrict__ g1, const float* __restrict__ be1,
    const float* __restrict__ g2, const float* __restrict__ be2,
    const float* __restrict__ g3, const float* __restrict__ be3,
    const float* __restrict__ g4, const float* __restrict__ be4,
    const float* __restrict__ dpar, const float* __restrict__ woutp,
    const float* __restrict__ skipp, float* __restrict__ ws,
    float* __restrict__ out)
{
    __shared__ __align__(16) float sY[128 * 36];     // y, then gated g
    __shared__ __align__(16) float sB[32 * 16];
    __shared__ __align__(16) float sC[32 * 16];
    int bid = blockIdx.x;
    int seq = bid >> 5, ch = bid & 31;
    int branch = seq >> 3, b = seq & 7;
    int lb = ch * 32;
    int tid = threadIdx.x;
    int sq = tid & 3;
    int d0 = (tid >> 2) * 2, s0 = sq * 4;

    float a2[8];
    a2_preload(alog, d0, s0, a2);

    const float* Bmg = ws + O_BM + (size_t)seq * 16384;
    const float* Cmg = ws + O_CM + (size_t)seq * 16384;
    for (int i = tid; i < 512; i += 256) {
        int s = i >> 5, li = i & 31;
        sB[li * 16 + s] = Bmg[(size_t)s * 1024 + lb + li];
        sC[li * 16 + s] = Cmg[(size_t)s * 1024 + lb + li];
    }

    const float* hp = ws + O_HP + (size_t)(seq * 32 + ch) * 4096;
    float4 H0 = *(const float4*)&hp[d0 * 16 + s0];
    float4 H1 = *(const float4*)&hp[(d0 + 1) * 16 + s0];
    float h[8] = {H0.x, H0.y, H0.z, H0.w, H1.x, H1.y, H1.z, H1.w};
    __syncthreads();

    const float* r0t = ws + O_DT + (size_t)seq * 131072 + (size_t)d0 * 1024 + lb;
    const float* r1t = r0t + 1024;
    const float* r0x = ws + O_DX + (size_t)seq * 131072 + (size_t)d0 * 1024 + lb;
    const float* r1x = r0x + 1024;

    // ---- rescan: y into sY (stride 36) ----
    for (int q4 = 0; q4 < 8; ++q4) {
        float4 t0 = *(const float4*)&r0t[q4 * 4];
        float4 t1 = *(const float4*)&r1t[q4 * 4];
        float4 x0v = *(const float4*)&r0x[q4 * 4];
        float4 x1v = *(const float4*)&r1x[q4 * 4];
        float t0a[4] = {t0.x, t0.y, t0.z, t0.w};
        float t1a[4] = {t1.x, t1.y, t1.z, t1.w};
        float x0a[4] = {x0v.x, x0v.y, x0v.z, x0v.w};
        float x1a[4] = {x1v.x, x1v.y, x1v.z, x1v.w};
#pragma unroll
        for (int k = 0; k < 4; ++k) {
            int li = q4 * 4 + k;
            float dt0 = t0a[k], dt1 = t1a[k];
            float dx0 = x0a[k], dx1 = x1a[k];
            float4 Bv = *(const float4*)&sB[li * 16 + s0];
            float4 Cv = *(const float4*)&sC[li * 16 + s0];
            float bv[4] = {Bv.x, Bv.y, Bv.z, Bv.w};
            float cv[4] = {Cv.x, Cv.y, Cv.z, Cv.w};
            float acc0 = 0.f, acc1 = 0.f;
#pragma unroll
            for (int ss = 0; ss < 4; ++ss) {
                float e0 = fexp2(dt0 * a2[ss]);
                h[ss] = e0 * h[ss] + dx0 * bv[ss];
                acc0 += h[ss] * cv[ss];
                float e1 = fexp2(dt1 * a2[4 + ss]);
                h[4 + ss] = e1 * h[4 + ss] + dx1 * bv[ss];
                acc1 += h[4 + ss] * cv[ss];
            }
            acc0 += __shfl_xor(acc0, 1); acc0 += __shfl_xor(acc0, 2);
            acc1 += __shfl_xor(acc1, 1); acc1 += __shfl_xor(acc1, 2);
            if (sq == 0) {
                sY[d0 * 36 + li]       = acc0;
                sY[(d0 + 1) * 36 + li] = acc1;
            }
        }
    }
    __syncthreads();

    // ---- gate in place: g = (y + D*xc) * silu(z) ----
    const float* zzg = ws + O_Z  + (size_t)seq * 131072;
    const float* xcg = ws + O_XC + (size_t)seq * 131072;
    for (int i = tid; i < 4096; i += 256) {
        int d = i >> 5, li = i & 31;
        float zv  = zzg[(size_t)d * 1024 + lb + li];
        float xcv = xcg[(size_t)d * 1024 + lb + li];
        float yv  = sY[d * 36 + li];
        sY[d * 36 + li] = (yv + dpar[d] * xcv) * (zv * sigmoidf_(zv));
    }
    __syncthreads();

    // ---- out-proj GEMM: out[64c][32p] = Wout[64][128] @ g[128][32] ----
    int ctt = tid >> 3;          // c0 = 2*ctt
    int ptq = tid & 7;           // p0 = 4*ptq
    int c0 = ctt * 2;
    const float* w0p = woutp + (size_t)c0 * 128;
    const float* w1p = w0p + 128;
    float acc[2][4];
#pragma unroll
    for (int i = 0; i < 2; ++i)
#pragma unroll
        for (int j = 0; j < 4; ++j) acc[i][j] = 0.f;
    for (int d4 = 0; d4 < 32; ++d4) {
        float4 wa = *(const float4*)&w0p[d4 * 4];
        float4 wb = *(const float4*)&w1p[d4 * 4];
        float waa[4] = {wa.x, wa.y, wa.z, wa.w};
        float wba[4] = {wb.x, wb.y, wb.z, wb.w};
#pragma unroll
        for (int k = 0; k < 4; ++k) {
            int d = d4 * 4 + k;
            float4 gv = *(const float4*)&sY[d * 36 + ptq * 4];
            acc[0][0] += waa[k] * gv.x; acc[0][1] += waa[k] * gv.y;
            acc[0][2] += waa[k] * gv.z; acc[0][3] += waa[k] * gv.w;
            acc[1][0] += wba[k] * gv.x; acc[1][1] += wba[k] * gv.y;
            acc[1][2] += wba[k] * gv.z; acc[1][3] += wba[k] * gv.w;
        }
    }

    // ---- epilogue: + skip * xn ----
    const float* xin = (branch==0)?x0:(branch==1)?x1:(branch==2)?x2:x3;
    const float* gam = (branch==0)?g1:(branch==1)?g2:(branch==2)?g3:g4;
    const float* bet = (branch==0)?be1:(branch==1)?be2:(branch==2)?be3:be4;
    const float* xb = xin + (size_t)b * 65536;
    int pp = lb + ptq * 4;
    float skipv = skipp[0];
    float4 m4 = *(const float4*)&ws[O_M  + (size_t)seq * 1024 + pp];
    float4 r4 = *(const float4*)&ws[O_RS + (size_t)seq * 1024 + pp];
    float mm[4] = {m4.x, m4.y, m4.z, m4.w};
    float rr[4] = {r4.x, r4.y, r4.z, r4.w};
#pragma unroll
    for (int ci = 0; ci < 2; ++ci) {
        int c = c0 + ci;
        float4 xv = *(const float4*)&xb[(size_t)c * 1024 + pp];
        float xvv[4] = {xv.x, xv.y, xv.z, xv.w};
        float gc = gam[c], bc = bet[c];
        float o[4];
#pragma unroll
        for (int pi = 0; pi < 4; ++pi) {
            float xn = (xvv[pi] - mm[pi]) * rr[pi] * gc + bc;
            o[pi] = acc[ci][pi] + skipv * xn;
        }
        *(float4*)&out[((size_t)b * 256 + branch * 64 + c) * 1024 + pp] =
            make_float4(o[0], o[1], o[2], o[3]);
    }
}

// ---------------- launch ----------------
extern "C" void kernel_launch(void* const* d_in, const int* in_sizes, int n_in,
                              void* d_out, int out_size, void* d_ws, size_t ws_size,
                              hipStream_t stream) {
    float* ws = (float*)d_ws;
    auto f = [&](int i) { return (const float*)d_in[i]; };
    hipLaunchKernelGGL(k1_ln_inproj, dim3(512), dim3(256), 0, stream,
        f(0), f(1), f(2), f(3), f(13),
        f(4), f(5), f(6), f(7), f(8), f(9), f(10), f(11), ws);
    hipLaunchKernelGGL(k2_conv_proj, dim3(512), dim3(256), 0, stream,
        f(14), f(15), f(16), f(17), f(18), f(19), ws);
    hipLaunchKernelGGL(k3b_compose, dim3(256), dim3(256), 0, stream, ws);
    hipLaunchKernelGGL(k3cd, dim3(1024), dim3(256), 0, stream,
        f(19),
        f(0), f(1), f(2), f(3),
        f(4), f(5), f(6), f(7), f(8), f(9), f(10), f(11),
        f(20), f(21), f(12), ws, (float*)d_out);
}